// Round 22
// baseline (193.878 us; speedup 1.0000x reference)
//
#include <hip/hip_runtime.h>
#include <hip/hip_bf16.h>
#include <math.h>

#define N_ 1024
#define KNN_K 16
#define LN_EPS 1e-5f

typedef unsigned long long u64;
typedef unsigned int u32;
typedef __attribute__((ext_vector_type(4))) float f32x4;
typedef __attribute__((ext_vector_type(8))) short short8;
typedef __attribute__((ext_vector_type(2))) unsigned int u32x2;
typedef __attribute__((ext_vector_type(4))) unsigned int u32x4;

// Round-to-nearest-even bf16 helpers.
__device__ __forceinline__ u32 rn_hi32(float v) {  // bf16 bits in high half
  u32 u = __float_as_uint(v);
  return (u + 0x7FFFu + ((u >> 16) & 1u)) & 0xFFFF0000u;
}
__device__ __forceinline__ u32 rn_b16(float v) {   // bf16 bits as 16-bit value
  u32 u = __float_as_uint(v);
  return (u + 0x7FFFu + ((u >> 16) & 1u)) >> 16;
}
__device__ __forceinline__ u64 umin64(u64 a, u64 b) { return a < b ? a : b; }

// ---------------------------------------------------------------------------
// front: prep + knn + precompute.
// vs R21 (passed): knn section now processes 2 QUERIES PER WAVE (independent
// serial chains -> ILP hides bpermute latency; per-query logic byte-copied),
// and consume uses winner (lane,slot) decoded from m via small-int compares
// (R18-correctness-proven form). knn grid 4096 -> 2048 blocks.
// prep / ntr / precompute sections byte-identical to R21.
// ---------------------------------------------------------------------------
__global__ __launch_bounds__(256) void front_kernel(
    const float* __restrict__ Wh, u32x4* __restrict__ whi,
    u32x4* __restrict__ wlo, const int* __restrict__ mask,
    float* __restrict__ ntr, const float* __restrict__ points,
    int* __restrict__ knn, const float* __restrict__ x,
    const float* __restrict__ W0, const float* __restrict__ b0,
    float* __restrict__ p_c, float* __restrict__ p_n) {
  __shared__ float SM[4096];              // 16 KiB
  const int blk = blockIdx.x;
  const int t = threadIdx.x;

  if (blk < 8) {
    int idx = blk * 256 + t;
    int lane = idx & 63;
    int ks = (idx >> 6) & 1;
    int m = (idx >> 7) & 3;
    int li = idx >> 9;
    int o = 16 * m + (lane & 15);
    int k0 = 32 * ks + 8 * (lane >> 4);
    const float* w = Wh + li * 4096 + o * 64 + k0;
    u32x4 hi, lo;
#pragma unroll
    for (int j = 0; j < 4; j++) {
      float f0 = w[2 * j], f1 = w[2 * j + 1];
      u32 h0 = rn_hi32(f0);
      u32 h1 = rn_hi32(f1);
      float l0 = f0 - __uint_as_float(h0);
      float l1 = f1 - __uint_as_float(h1);
      hi[j] = (h0 >> 16) | h1;
      lo[j] = rn_b16(l0) | (rn_b16(l1) << 16);
    }
    int fi = ((li * 4 + m) * 2 + ks) * 64 + lane;
    whi[fi] = hi;
    wlo[fi] = lo;
  } else if (blk < 24) {
    int b = blk - 8;
    int s = 0;
    for (int e = t; e < N_; e += 256) s += mask[b * N_ + e];
    for (int off = 32; off; off >>= 1) s += __shfl_xor(s, off, 64);
    int* accI = (int*)SM;
    int wave = t >> 6, lane = t & 63;
    if (lane == 0) accI[wave] = s;
    __syncthreads();
    if (t == 0) ntr[b] = (float)(accI[0] + accI[1] + accI[2] + accI[3]);
  } else if (blk < 24 + 2048) {
#pragma clang fp contract(off)
    float* px = SM;
    float* py = SM + 1024;
    float* pz = SM + 2048;
    float* minf = SM + 3072;
    int kb = blk - 24;
    int b = kb >> 7;                      // 128 blocks per batch
    int qbase = (kb & 127) << 3;          // 8 queries per block
    for (int j = t; j < N_; j += 256) {
      const float* p = points + ((size_t)(b * N_ + j)) * 3;
      px[j] = p[0];
      py[j] = p[1];
      pz[j] = p[2];
      minf[j] = mask[b * N_ + j] ? 0.0f : __builtin_inff();
    }
    __syncthreads();
    int wave = t >> 6, lane = t & 63;
    // two independent queries per wave (ILP over the serial reduce chains)
    int n0 = qbase + wave;
    int n1 = qbase + 4 + wave;
    float qx0 = px[n0], qy0 = py[n0], qz0 = pz[n0];
    float qx1 = px[n1], qy1 = py[n1], qz1 = pz[n1];
    u64 key0[16], key1[16];
#pragma unroll
    for (int c = 0; c < 16; c++) {
      int j = lane + (c << 6);
      float fx = px[j], fy = py[j], fz = pz[j], mf = minf[j];
      float dx0 = qx0 - fx, dy0 = qy0 - fy, dz0 = qz0 - fz;
      float d20 = dx0 * dx0 + dy0 * dy0 + dz0 * dz0;
      d20 = d20 + mf;
      key0[c] = ((u64)__float_as_uint(d20) << 32) | (u32)j;
      float dx1 = qx1 - fx, dy1 = qy1 - fy, dz1 = qz1 - fz;
      float d21 = dx1 * dx1 + dy1 * dy1 + dz1 * dz1;
      d21 = d21 + mf;
      key1[c] = ((u64)__float_as_uint(d21) << 32) | (u32)j;
    }
    int* dst0 = knn + ((size_t)(b * N_ + n0)) * KNN_K;
    int* dst1 = knn + ((size_t)(b * N_ + n1)) * KNN_K;
    for (int s = 0; s < 16; s++) {
      // ---- query 0: depth-4 tree min (exact; min associative) ----
      u64 m0, m1;
      {
        u64 a0 = umin64(key0[0], key0[1]);
        u64 a1 = umin64(key0[2], key0[3]);
        u64 a2 = umin64(key0[4], key0[5]);
        u64 a3 = umin64(key0[6], key0[7]);
        u64 a4 = umin64(key0[8], key0[9]);
        u64 a5 = umin64(key0[10], key0[11]);
        u64 a6 = umin64(key0[12], key0[13]);
        u64 a7 = umin64(key0[14], key0[15]);
        m0 = umin64(umin64(umin64(a0, a1), umin64(a2, a3)),
                    umin64(umin64(a4, a5), umin64(a6, a7)));
      }
      {
        u64 a0 = umin64(key1[0], key1[1]);
        u64 a1 = umin64(key1[2], key1[3]);
        u64 a2 = umin64(key1[4], key1[5]);
        u64 a3 = umin64(key1[6], key1[7]);
        u64 a4 = umin64(key1[8], key1[9]);
        u64 a5 = umin64(key1[10], key1[11]);
        u64 a6 = umin64(key1[12], key1[13]);
        u64 a7 = umin64(key1[14], key1[15]);
        m1 = umin64(umin64(umin64(a0, a1), umin64(a2, a3)),
                    umin64(umin64(a4, a5), umin64(a6, a7)));
      }
      // ---- interleaved wave reduces (independent chains) ----
#pragma unroll
      for (int off = 32; off; off >>= 1) {
        u64 o0 = __shfl_xor(m0, off, 64);
        u64 o1 = __shfl_xor(m1, off, 64);
        if (o0 < m0) m0 = o0;
        if (o1 < m1) m1 = o1;
      }
      if (lane == 0) {
        dst0[s] = (int)(m0 & 0xFFFFFFFFu);
        dst1[s] = (int)(m1 & 0xFFFFFFFFu);
      }
      // ---- consume via decoded winner (R18-proven form) ----
      int wl0 = (int)(m0 & 63u), wc0 = (int)((m0 >> 6) & 15u);
      int wl1 = (int)(m1 & 63u), wc1 = (int)((m1 >> 6) & 15u);
#pragma unroll
      for (int c = 0; c < 16; c++) {
        if (lane == wl0 && c == wc0) key0[c] = ~0ULL;
        if (lane == wl1 && c == wc1) key1[c] = ~0ULL;
      }
    }
  } else {
    float* W = SM;                        // one 64x64 matrix at a time
    int pb = blk - (24 + 2048);
    int wave = t >> 6, lane = t & 63;
    int pbase = pb * 64 + wave * 16;
    // ---- pass A: Wc = W0a + W0b -> p_c ----
    for (int e = t; e < 4096; e += 256) {
      int o = e & 63, i = e >> 6;         // stride-1 LDS writes
      W[i * 64 + o] = W0[o * 128 + i] + W0[o * 128 + 64 + i];
    }
    __syncthreads();
    for (int it = 0; it < 16; it++) {
      int p = pbase + it;
      const float* xr = x + (size_t)__builtin_amdgcn_readfirstlane(p) * 64;
      float pc = b0[lane];
#pragma unroll
      for (int i = 0; i < 64; i++) pc = fmaf(xr[i], W[i * 64 + lane], pc);
      p_c[(size_t)p * 64 + lane] = pc;
    }
    __syncthreads();                      // WAR: reads done before reload
    // ---- pass B: Wn = W0b -> p_n ----
    for (int e = t; e < 4096; e += 256) {
      int o = e & 63, i = e >> 6;
      W[i * 64 + o] = W0[o * 128 + 64 + i];
    }
    __syncthreads();
    for (int it = 0; it < 16; it++) {
      int p = pbase + it;
      const float* xr = x + (size_t)__builtin_amdgcn_readfirstlane(p) * 64;
      float pn = 0.0f;
#pragma unroll
      for (int i = 0; i < 64; i++) pn = fmaf(xr[i], W[i * 64 + lane], pn);
      p_n[(size_t)p * 64 + lane] = pn;
    }
  }
}

// ---------------------------------------------------------------------------
// layerA — BYTE-IDENTICAL to R20/R21 (passed): layer0 + hidden-0 fused.
// ---------------------------------------------------------------------------
__global__ __launch_bounds__(128) void layerA_kernel(
    const float* __restrict__ p_c, const float* __restrict__ p_n,
    const int* __restrict__ knn_, const u32x4* __restrict__ whi,
    const u32x4* __restrict__ wlo, const float* __restrict__ bh,
    const float* __restrict__ ln_g, const float* __restrict__ ln_b,
    const float* __restrict__ prelu_a, u32* __restrict__ Hout) {
  const int t = threadIdx.x;
  const int wv = t >> 6, l = t & 63;
  const int c = l & 15;
  const int g = l >> 4;
  const int pbase = blockIdx.x * 8 + wv * 4;
  const int b = pbase >> 10;

  u32x4 bhi[4][2], blo[4][2];

  {
    float h[64];
    int p0 = pbase + g;
    int j = knn_[(size_t)p0 * 16 + c];
    const float4* pc4 = reinterpret_cast<const float4*>(p_c + (size_t)p0 * 64);
    const float4* pn4 = reinterpret_cast<const float4*>(p_n + (size_t)((b << 10) + j) * 64);
#pragma unroll
    for (int q = 0; q < 16; q++) {
      float4 a = pc4[q], v = pn4[q];
      h[q * 4 + 0] = a.x - v.x;
      h[q * 4 + 1] = a.y - v.y;
      h[q * 4 + 2] = a.z - v.z;
      h[q * 4 + 3] = a.w - v.w;
    }
    float s = 0.0f, s2 = 0.0f;
#pragma unroll
    for (int o = 0; o < 64; o++) { s += h[o]; s2 += h[o] * h[o]; }
    float mu = s * (1.0f / 64.0f);
    float var = s2 * (1.0f / 64.0f) - mu * mu;
    float inv = rsqrtf(var + LN_EPS);
    float aslope = prelu_a[0];
#pragma unroll
    for (int o = 0; o < 64; o++) {
      float v = ln_g[o] * ((h[o] - mu) * inv) + ln_b[o];
      h[o] = v > 0.0f ? v : aslope * v;
    }
    u32 hpk_hi[32], hpk_lo[32];
#pragma unroll
    for (int w = 0; w < 32; w++) {
      float f0 = h[2 * w], f1 = h[2 * w + 1];
      u32 h0 = rn_hi32(f0);
      u32 h1 = rn_hi32(f1);
      float l0 = f0 - __uint_as_float(h0);
      float l1 = f1 - __uint_as_float(h1);
      hpk_hi[w] = (h0 >> 16) | h1;
      hpk_lo[w] = rn_b16(l0) | (rn_b16(l1) << 16);
    }
#pragma unroll
    for (int nt = 0; nt < 4; nt++) {
      int src = c + 16 * nt;
#pragma unroll
      for (int ks = 0; ks < 2; ks++)
#pragma unroll
        for (int gw = 0; gw < 4; gw++)
#pragma unroll
          for (int j2 = 0; j2 < 4; j2++) {
            u32 th = (u32)__shfl((int)hpk_hi[16 * ks + 4 * gw + j2], src, 64);
            u32 tl = (u32)__shfl((int)hpk_lo[16 * ks + 4 * gw + j2], src, 64);
            if (g == gw) {
              bhi[nt][ks][j2] = th;
              blo[nt][ks][j2] = tl;
            }
          }
    }
  }

  const int li = 0;
  f32x4 bias4[4];
#pragma unroll
  for (int m = 0; m < 4; m++)
    bias4[m] = *(const f32x4*)(bh + li * 64 + 16 * m + 4 * g);

  f32x4 acc[4][4];
#pragma unroll
  for (int m = 0; m < 4; m++)
#pragma unroll
    for (int nt = 0; nt < 4; nt++) acc[m][nt] = bias4[m];

#pragma unroll
  for (int ks = 0; ks < 2; ks++)
#pragma unroll
    for (int m = 0; m < 4; m++) {
      int fi = ((li * 4 + m) * 2 + ks) * 64 + l;
      short8 ah = __builtin_bit_cast(short8, whi[fi]);
      short8 al = __builtin_bit_cast(short8, wlo[fi]);
#pragma unroll
      for (int nt = 0; nt < 4; nt++) {
        short8 bh_ = __builtin_bit_cast(short8, bhi[nt][ks]);
        short8 bl_ = __builtin_bit_cast(short8, blo[nt][ks]);
        acc[m][nt] = __builtin_amdgcn_mfma_f32_16x16x32_bf16(ah, bh_, acc[m][nt], 0, 0, 0);
        acc[m][nt] = __builtin_amdgcn_mfma_f32_16x16x32_bf16(ah, bl_, acc[m][nt], 0, 0, 0);
        acc[m][nt] = __builtin_amdgcn_mfma_f32_16x16x32_bf16(al, bh_, acc[m][nt], 0, 0, 0);
      }
    }

  f32x4 g4[4], b4[4];
#pragma unroll
  for (int m = 0; m < 4; m++) {
    g4[m] = *(const f32x4*)(ln_g + (li + 1) * 64 + 16 * m + 4 * g);
    b4[m] = *(const f32x4*)(ln_b + (li + 1) * 64 + 16 * m + 4 * g);
  }
  float aslope = prelu_a[li + 1];
#pragma unroll
  for (int nt = 0; nt < 4; nt++) {
    float s = 0.0f, s2 = 0.0f;
#pragma unroll
    for (int m = 0; m < 4; m++)
#pragma unroll
      for (int v = 0; v < 4; v++) {
        float x = acc[m][nt][v];
        s += x;
        s2 = fmaf(x, x, s2);
      }
    s += __shfl_xor(s, 16, 64);
    s2 += __shfl_xor(s2, 16, 64);
    s += __shfl_xor(s, 32, 64);
    s2 += __shfl_xor(s2, 32, 64);
    float mu = s * (1.0f / 64.0f);
    float var = s2 * (1.0f / 64.0f) - mu * mu;
    float inv = rsqrtf(var + LN_EPS);
#pragma unroll
    for (int m = 0; m < 4; m++)
#pragma unroll
      for (int v = 0; v < 4; v++) {
        float x = (acc[m][nt][v] - mu) * inv;
        x = g4[m][v] * x + b4[m][v];
        acc[m][nt][v] = x > 0.0f ? x : aslope * x;
      }
  }

#pragma unroll
  for (int nt = 0; nt < 4; nt++) {
    size_t eb = ((size_t)(pbase + nt) * 16 + c) * 32;
#pragma unroll
    for (int m = 0; m < 4; m++) {
      u32x2 v;
      v[0] = rn_b16(acc[m][nt][0]) | (rn_b16(acc[m][nt][1]) << 16);
      v[1] = rn_b16(acc[m][nt][2]) | (rn_b16(acc[m][nt][3]) << 16);
      *(u32x2*)(Hout + eb + 8 * m + 2 * g) = v;
    }
  }
}

// ---------------------------------------------------------------------------
// layer (global path): BYTE-IDENTICAL to R17 (passed). Double-buffered H.
// ---------------------------------------------------------------------------
__global__ __launch_bounds__(128) void layer_kernel(
    const u32* __restrict__ Hin, u32* __restrict__ Hout,
    const u32x4* __restrict__ whi, const u32x4* __restrict__ wlo,
    const float* __restrict__ bh, const float* __restrict__ ln_g,
    const float* __restrict__ ln_b, const float* __restrict__ prelu_a,
    const float* __restrict__ ntr, float* __restrict__ out, int li, int last) {
  const int t = threadIdx.x;
  const int wv = t >> 6, l = t & 63;
  const int c = l & 15;
  const int g = l >> 4;
  const int pbase = blockIdx.x * 8 + wv * 4;
  const int b = pbase >> 10;

  u32x4 bw[4][2];
#pragma unroll
  for (int nt = 0; nt < 4; nt++) {
    size_t eb = ((size_t)(pbase + nt) * 16 + c) * 32;
#pragma unroll
    for (int ks = 0; ks < 2; ks++)
      bw[nt][ks] = *(const u32x4*)(Hin + eb + 16 * ks + 4 * g);
  }

  f32x4 bias4[4];
#pragma unroll
  for (int m = 0; m < 4; m++)
    bias4[m] = *(const f32x4*)(bh + li * 64 + 16 * m + 4 * g);

  f32x4 acc[4][4];  // [m][nt]
#pragma unroll
  for (int m = 0; m < 4; m++)
#pragma unroll
    for (int nt = 0; nt < 4; nt++) acc[m][nt] = bias4[m];

#pragma unroll
  for (int ks = 0; ks < 2; ks++)
#pragma unroll
    for (int m = 0; m < 4; m++) {
      int fi = ((li * 4 + m) * 2 + ks) * 64 + l;
      short8 ah = __builtin_bit_cast(short8, whi[fi]);
      short8 al = __builtin_bit_cast(short8, wlo[fi]);
#pragma unroll
      for (int nt = 0; nt < 4; nt++) {
        short8 bb = __builtin_bit_cast(short8, bw[nt][ks]);
        acc[m][nt] = __builtin_amdgcn_mfma_f32_16x16x32_bf16(ah, bb, acc[m][nt], 0, 0, 0);
        acc[m][nt] = __builtin_amdgcn_mfma_f32_16x16x32_bf16(al, bb, acc[m][nt], 0, 0, 0);
      }
    }

  f32x4 g4[4], b4[4];
#pragma unroll
  for (int m = 0; m < 4; m++) {
    g4[m] = *(const f32x4*)(ln_g + (li + 1) * 64 + 16 * m + 4 * g);
    b4[m] = *(const f32x4*)(ln_b + (li + 1) * 64 + 16 * m + 4 * g);
  }
  float aslope = prelu_a[li + 1];
#pragma unroll
  for (int nt = 0; nt < 4; nt++) {
    float s = 0.0f, s2 = 0.0f;
#pragma unroll
    for (int m = 0; m < 4; m++)
#pragma unroll
      for (int v = 0; v < 4; v++) {
        float x = acc[m][nt][v];
        s += x;
        s2 = fmaf(x, x, s2);
      }
    s += __shfl_xor(s, 16, 64);
    s2 += __shfl_xor(s2, 16, 64);
    s += __shfl_xor(s, 32, 64);
    s2 += __shfl_xor(s2, 32, 64);
    float mu = s * (1.0f / 64.0f);
    float var = s2 * (1.0f / 64.0f) - mu * mu;
    float inv = rsqrtf(var + LN_EPS);
#pragma unroll
    for (int m = 0; m < 4; m++)
#pragma unroll
      for (int v = 0; v < 4; v++) {
        float x = (acc[m][nt][v] - mu) * inv;
        x = g4[m][v] * x + b4[m][v];
        acc[m][nt][v] = x > 0.0f ? x : aslope * x;
      }
  }

  if (!last) {
#pragma unroll
    for (int nt = 0; nt < 4; nt++) {
      size_t eb = ((size_t)(pbase + nt) * 16 + c) * 32;
#pragma unroll
      for (int m = 0; m < 4; m++) {
        u32x2 v;
        v[0] = rn_b16(acc[m][nt][0]) | (rn_b16(acc[m][nt][1]) << 16);
        v[1] = rn_b16(acc[m][nt][2]) | (rn_b16(acc[m][nt][3]) << 16);
        *(u32x2*)(Hout + eb + 8 * m + 2 * g) = v;
      }
    }
  } else {
    float cnt = ntr[b];
    float n_safe = (cnt == 0.0f) ? 1.0f : cnt;
    float rinv = 1.0f / n_safe;
    float msk = ((float)c < cnt) ? 1.0f : 0.0f;
#pragma unroll
    for (int nt = 0; nt < 4; nt++)
#pragma unroll
      for (int m = 0; m < 4; m++) {
        f32x4 r;
#pragma unroll
        for (int v = 0; v < 4; v++) {
          float x = acc[m][nt][v] * msk;
          x += __shfl_xor(x, 1, 64);
          x += __shfl_xor(x, 2, 64);
          x += __shfl_xor(x, 4, 64);
          x += __shfl_xor(x, 8, 64);
          r[v] = x * rinv;
        }
        if (c == 0)
          *(f32x4*)(out + (size_t)(pbase + nt) * 64 + 16 * m + 4 * g) = r;
      }
  }
}

// ---------------------------------------------------------------------------
// mlp_mfma3 — BYTE-EXACT R11/R13 kernel (passed 3x). FALLBACK path.
// ---------------------------------------------------------------------------
__global__ __launch_bounds__(128) void mlp_mfma3_kernel(
    const float* __restrict__ p_c, const float* __restrict__ p_n,
    const int* __restrict__ knn_, const u32x4* __restrict__ whi,
    const u32x4* __restrict__ wlo, const float* __restrict__ bh,
    const float* __restrict__ ln_g, const float* __restrict__ ln_b,
    const float* __restrict__ prelu_a, const float* __restrict__ ntr,
    float* __restrict__ out) {
  const int t = threadIdx.x;
  const int wv = t >> 6, l = t & 63;
  const int c = l & 15;
  const int g = l >> 4;
  const int pbase = blockIdx.x * 8 + wv * 4;
  const int b = pbase >> 10;

  u32x4 bhi[4][2], blo[4][2];

  {
    float h[64];
    int p0 = pbase + g;
    int j = knn_[(size_t)p0 * 16 + c];
    const float4* pc4 = reinterpret_cast<const float4*>(p_c + (size_t)p0 * 64);
    const float4* pn4 = reinterpret_cast<const float4*>(p_n + (size_t)((b << 10) + j) * 64);
#pragma unroll
    for (int q = 0; q < 16; q++) {
      float4 a = pc4[q], v = pn4[q];
      h[q * 4 + 0] = a.x - v.x;
      h[q * 4 + 1] = a.y - v.y;
      h[q * 4 + 2] = a.z - v.z;
      h[q * 4 + 3] = a.w - v.w;
    }
    float s = 0.0f, s2 = 0.0f;
#pragma unroll
    for (int o = 0; o < 64; o++) { s += h[o]; s2 += h[o] * h[o]; }
    float mu = s * (1.0f / 64.0f);
    float var = s2 * (1.0f / 64.0f) - mu * mu;
    float inv = rsqrtf(var + LN_EPS);
    float aslope = prelu_a[0];
#pragma unroll
    for (int o = 0; o < 64; o++) {
      float v = ln_g[o] * ((h[o] - mu) * inv) + ln_b[o];
      h[o] = v > 0.0f ? v : aslope * v;
    }
    u32 hpk_hi[32], hpk_lo[32];
#pragma unroll
    for (int w = 0; w < 32; w++) {
      float f0 = h[2 * w], f1 = h[2 * w + 1];
      u32 h0 = rn_hi32(f0);
      u32 h1 = rn_hi32(f1);
      float l0 = f0 - __uint_as_float(h0);
      float l1 = f1 - __uint_as_float(h1);
      hpk_hi[w] = (h0 >> 16) | h1;
      hpk_lo[w] = rn_b16(l0) | (rn_b16(l1) << 16);
    }
#pragma unroll
    for (int nt = 0; nt < 4; nt++) {
      int src = c + 16 * nt;
#pragma unroll
      for (int ks = 0; ks < 2; ks++)
#pragma unroll
        for (int gw = 0; gw < 4; gw++)
#pragma unroll
          for (int j2 = 0; j2 < 4; j2++) {
            u32 th = (u32)__shfl((int)hpk_hi[16 * ks + 4 * gw + j2], src, 64);
            u32 tl = (u32)__shfl((int)hpk_lo[16 * ks + 4 * gw + j2], src, 64);
            if (g == gw) {
              bhi[nt][ks][j2] = th;
              blo[nt][ks][j2] = tl;
            }
          }
    }
  }

  float cnt = ntr[b];

#pragma unroll 1
  for (int li = 0; li < 4; li++) {
    f32x4 bias4[4];
#pragma unroll
    for (int m = 0; m < 4; m++)
      bias4[m] = *(const f32x4*)(bh + li * 64 + 16 * m + 4 * g);

    f32x4 acc[4][4];
#pragma unroll
    for (int m = 0; m < 4; m++)
#pragma unroll
      for (int nt = 0; nt < 4; nt++) acc[m][nt] = bias4[m];

#pragma unroll
    for (int ks = 0; ks < 2; ks++)
#pragma unroll
      for (int m = 0; m < 4; m++) {
        int fi = ((li * 4 + m) * 2 + ks) * 64 + l;
        short8 ah = __builtin_bit_cast(short8, whi[fi]);
        short8 al = __builtin_bit_cast(short8, wlo[fi]);
#pragma unroll
        for (int nt = 0; nt < 4; nt++) {
          short8 bh_ = __builtin_bit_cast(short8, bhi[nt][ks]);
          short8 bl_ = __builtin_bit_cast(short8, blo[nt][ks]);
          acc[m][nt] = __builtin_amdgcn_mfma_f32_16x16x32_bf16(ah, bh_, acc[m][nt], 0, 0, 0);
          acc[m][nt] = __builtin_amdgcn_mfma_f32_16x16x32_bf16(ah, bl_, acc[m][nt], 0, 0, 0);
          acc[m][nt] = __builtin_amdgcn_mfma_f32_16x16x32_bf16(al, bh_, acc[m][nt], 0, 0, 0);
        }
      }

    f32x4 g4[4], b4[4];
#pragma unroll
    for (int m = 0; m < 4; m++) {
      g4[m] = *(const f32x4*)(ln_g + (li + 1) * 64 + 16 * m + 4 * g);
      b4[m] = *(const f32x4*)(ln_b + (li + 1) * 64 + 16 * m + 4 * g);
    }
    float aslope = prelu_a[li + 1];
#pragma unroll
    for (int nt = 0; nt < 4; nt++) {
      float s = 0.0f, s2 = 0.0f;
#pragma unroll
      for (int m = 0; m < 4; m++)
#pragma unroll
        for (int v = 0; v < 4; v++) {
          float x = acc[m][nt][v];
          s += x;
          s2 = fmaf(x, x, s2);
        }
      s += __shfl_xor(s, 16, 64);
      s2 += __shfl_xor(s2, 16, 64);
      s += __shfl_xor(s, 32, 64);
      s2 += __shfl_xor(s2, 32, 64);
      float mu = s * (1.0f / 64.0f);
      float var = s2 * (1.0f / 64.0f) - mu * mu;
      float inv = rsqrtf(var + LN_EPS);
#pragma unroll
      for (int m = 0; m < 4; m++)
#pragma unroll
        for (int v = 0; v < 4; v++) {
          float x = (acc[m][nt][v] - mu) * inv;
          x = g4[m][v] * x + b4[m][v];
          acc[m][nt][v] = x > 0.0f ? x : aslope * x;
        }
    }

    if (li < 3) {
      float h[64];
#pragma unroll
      for (int o = 0; o < 64; o++) {
        int srcl = c + 16 * ((o >> 2) & 3);
#pragma unroll
        for (int ntp = 0; ntp < 4; ntp++) {
          float tv = __shfl(acc[o >> 4][ntp][o & 3], srcl, 64);
          if (g == ntp) h[o] = tv;
        }
      }
      u32 hpk_hi[32], hpk_lo[32];
#pragma unroll
      for (int w = 0; w < 32; w++) {
        float f0 = h[2 * w], f1 = h[2 * w + 1];
        u32 h0 = rn_hi32(f0);
        u32 h1 = rn_hi32(f1);
        float l0 = f0 - __uint_as_float(h0);
        float l1 = f1 - __uint_as_float(h1);
        hpk_hi[w] = (h0 >> 16) | h1;
        hpk_lo[w] = rn_b16(l0) | (rn_b16(l1) << 16);
      }
#pragma unroll
      for (int nt = 0; nt < 4; nt++) {
        int src = c + 16 * nt;
#pragma unroll
        for (int ks = 0; ks < 2; ks++)
#pragma unroll
          for (int gw = 0; gw < 4; gw++)
#pragma unroll
            for (int j2 = 0; j2 < 4; j2++) {
              u32 th = (u32)__shfl((int)hpk_hi[16 * ks + 4 * gw + j2], src, 64);
              u32 tl = (u32)__shfl((int)hpk_lo[16 * ks + 4 * gw + j2], src, 64);
              if (g == gw) {
                bhi[nt][ks][j2] = th;
                blo[nt][ks][j2] = tl;
              }
            }
      }
    } else {
      float n_safe = (cnt == 0.0f) ? 1.0f : cnt;
      float rinv = 1.0f / n_safe;
      float msk = ((float)c < cnt) ? 1.0f : 0.0f;
#pragma unroll
      for (int nt = 0; nt < 4; nt++)
#pragma unroll
        for (int m = 0; m < 4; m++) {
          f32x4 r;
#pragma unroll
          for (int v = 0; v < 4; v++) {
            float x = acc[m][nt][v] * msk;
            x += __shfl_xor(x, 1, 64);
            x += __shfl_xor(x, 2, 64);
            x += __shfl_xor(x, 4, 64);
            x += __shfl_xor(x, 8, 64);
            r[v] = x * rinv;
          }
          if (c == 0)
            *(f32x4*)(out + (size_t)(pbase + nt) * 64 + 16 * m + 4 * g) = r;
        }
    }
  }
}

// ---------------------------------------------------------------------------
extern "C" void kernel_launch(void* const* d_in, const int* in_sizes, int n_in,
                              void* d_out, int out_size, void* d_ws, size_t ws_size,
                              hipStream_t stream) {
  const float* points  = (const float*)d_in[0];
  const float* x       = (const float*)d_in[1];
  const int*   mask    = (const int*)d_in[2];
  const float* W0      = (const float*)d_in[3];
  const float* b0      = (const float*)d_in[4];
  const float* Wh      = (const float*)d_in[5];
  const float* bh      = (const float*)d_in[6];
  const float* ln_g    = (const float*)d_in[7];
  const float* ln_b    = (const float*)d_in[8];
  const float* prelu_a = (const float*)d_in[9];
  float* out = (float*)d_out;

  char* ws = (char*)d_ws;
  int*   knn  = (int*)ws;                                    // 1 MB
  float* p_c  = (float*)(ws + (1 << 20));                    // 4 MB
  float* p_n  = (float*)(ws + (1 << 20) + (4 << 20));        // 4 MB
  u32x4* whi  = (u32x4*)(ws + (9 << 20));                    // 32 KB
  u32x4* wlo  = (u32x4*)(ws + (9 << 20) + (32 << 10));       // 32 KB
  float* ntr  = (float*)(ws + (9 << 20) + (64 << 10));       // 64 B
  u32*   H0   = (u32*)(ws + ((size_t)10 << 20));             // 32 MB
  u32*   H1   = (u32*)(ws + ((size_t)42 << 20));             // 32 MB

  front_kernel<<<24 + 2048 + 256, 256, 0, stream>>>(
      Wh, whi, wlo, mask, ntr, points, knn, x, W0, b0, p_c, p_n);

  if (ws_size >= ((size_t)74 << 20)) {
    // global-transport path: layerA (layer0 + hidden-0 fused) + 3 layers
    layerA_kernel<<<2048, 128, 0, stream>>>(p_c, p_n, knn, whi, wlo, bh,
                                            ln_g, ln_b, prelu_a, H0);
    layer_kernel<<<2048, 128, 0, stream>>>(H0, H1, whi, wlo, bh, ln_g, ln_b,
                                           prelu_a, ntr, out, 1, 0);
    layer_kernel<<<2048, 128, 0, stream>>>(H1, H0, whi, wlo, bh, ln_g, ln_b,
                                           prelu_a, ntr, out, 2, 0);
    layer_kernel<<<2048, 128, 0, stream>>>(H0, H1, whi, wlo, bh, ln_g, ln_b,
                                           prelu_a, ntr, out, 3, 1);
  } else {
    // fallback: byte-exact R13 mlp (passed 3x)
    mlp_mfma3_kernel<<<2048, 128, 0, stream>>>(p_c, p_n, knn, whi, wlo, bh,
                                               ln_g, ln_b, prelu_a, ntr, out);
  }
}

// Round 23
// 188.646 us; speedup vs baseline: 1.0277x; 1.0277x over previous
//
#include <hip/hip_runtime.h>
#include <hip/hip_bf16.h>
#include <math.h>

#define N_ 1024
#define KNN_K 16
#define LN_EPS 1e-5f

typedef unsigned long long u64;
typedef unsigned int u32;
typedef __attribute__((ext_vector_type(4))) float f32x4;
typedef __attribute__((ext_vector_type(8))) short short8;
typedef __attribute__((ext_vector_type(2))) unsigned int u32x2;
typedef __attribute__((ext_vector_type(4))) unsigned int u32x4;

// Round-to-nearest-even bf16 helpers.
__device__ __forceinline__ u32 rn_hi32(float v) {  // bf16 bits in high half
  u32 u = __float_as_uint(v);
  return (u + 0x7FFFu + ((u >> 16) & 1u)) & 0xFFFF0000u;
}
__device__ __forceinline__ u32 rn_b16(float v) {   // bf16 bits as 16-bit value
  u32 u = __float_as_uint(v);
  return (u + 0x7FFFu + ((u >> 16) & 1u)) >> 16;
}
__device__ __forceinline__ u64 umin64(u64 a, u64 b) { return a < b ? a : b; }

// ---------------------------------------------------------------------------
// front: BYTE-EXACT R21 form (best verified: front 81.7us, total 188.6us).
// knn = 1 query/wave u64 tree-min (R18 u32-split and R22 2-query-ILP both
// regressed — this form is the measured local optimum).
// ---------------------------------------------------------------------------
__global__ __launch_bounds__(256) void front_kernel(
    const float* __restrict__ Wh, u32x4* __restrict__ whi,
    u32x4* __restrict__ wlo, const int* __restrict__ mask,
    float* __restrict__ ntr, const float* __restrict__ points,
    int* __restrict__ knn, const float* __restrict__ x,
    const float* __restrict__ W0, const float* __restrict__ b0,
    float* __restrict__ p_c, float* __restrict__ p_n) {
  __shared__ float SM[4096];              // 16 KiB
  const int blk = blockIdx.x;
  const int t = threadIdx.x;

  if (blk < 8) {
    int idx = blk * 256 + t;
    int lane = idx & 63;
    int ks = (idx >> 6) & 1;
    int m = (idx >> 7) & 3;
    int li = idx >> 9;
    int o = 16 * m + (lane & 15);
    int k0 = 32 * ks + 8 * (lane >> 4);
    const float* w = Wh + li * 4096 + o * 64 + k0;
    u32x4 hi, lo;
#pragma unroll
    for (int j = 0; j < 4; j++) {
      float f0 = w[2 * j], f1 = w[2 * j + 1];
      u32 h0 = rn_hi32(f0);
      u32 h1 = rn_hi32(f1);
      float l0 = f0 - __uint_as_float(h0);
      float l1 = f1 - __uint_as_float(h1);
      hi[j] = (h0 >> 16) | h1;
      lo[j] = rn_b16(l0) | (rn_b16(l1) << 16);
    }
    int fi = ((li * 4 + m) * 2 + ks) * 64 + lane;
    whi[fi] = hi;
    wlo[fi] = lo;
  } else if (blk < 24) {
    int b = blk - 8;
    int s = 0;
    for (int e = t; e < N_; e += 256) s += mask[b * N_ + e];
    for (int off = 32; off; off >>= 1) s += __shfl_xor(s, off, 64);
    int* accI = (int*)SM;
    int wave = t >> 6, lane = t & 63;
    if (lane == 0) accI[wave] = s;
    __syncthreads();
    if (t == 0) ntr[b] = (float)(accI[0] + accI[1] + accI[2] + accI[3]);
  } else if (blk < 24 + 4096) {
#pragma clang fp contract(off)
    float* px = SM;
    float* py = SM + 1024;
    float* pz = SM + 2048;
    float* minf = SM + 3072;
    int kb = blk - 24;
    int b = kb >> 8;
    int qbase = (kb & 255) << 2;
    for (int j = t; j < N_; j += 256) {
      const float* p = points + ((size_t)(b * N_ + j)) * 3;
      px[j] = p[0];
      py[j] = p[1];
      pz[j] = p[2];
      minf[j] = mask[b * N_ + j] ? 0.0f : __builtin_inff();
    }
    __syncthreads();
    int wave = t >> 6, lane = t & 63;
    int n = qbase + wave;
    float qx = px[n], qy = py[n], qz = pz[n];
    u64 key[16];
#pragma unroll
    for (int c = 0; c < 16; c++) {
      int j = lane + (c << 6);
      float dx = qx - px[j];
      float dy = qy - py[j];
      float dz = qz - pz[j];
      float d2 = dx * dx + dy * dy + dz * dz;
      d2 = d2 + minf[j];
      key[c] = ((u64)__float_as_uint(d2) << 32) | (u32)j;
    }
    int* dst = knn + ((size_t)(b * N_ + n)) * KNN_K;
    for (int s = 0; s < 16; s++) {
      // depth-4 tree min over the 16 local keys (exact; min associative)
      u64 a0 = umin64(key[0], key[1]);
      u64 a1 = umin64(key[2], key[3]);
      u64 a2 = umin64(key[4], key[5]);
      u64 a3 = umin64(key[6], key[7]);
      u64 a4 = umin64(key[8], key[9]);
      u64 a5 = umin64(key[10], key[11]);
      u64 a6 = umin64(key[12], key[13]);
      u64 a7 = umin64(key[14], key[15]);
      u64 b0_ = umin64(a0, a1);
      u64 b1_ = umin64(a2, a3);
      u64 b2_ = umin64(a4, a5);
      u64 b3_ = umin64(a6, a7);
      u64 m = umin64(umin64(b0_, b1_), umin64(b2_, b3_));
#pragma unroll
      for (int off = 32; off; off >>= 1) {
        u64 o = __shfl_xor(m, off, 64);
        if (o < m) m = o;
      }
      if (lane == 0) dst[s] = (int)(m & 0xFFFFFFFFu);
#pragma unroll
      for (int c = 0; c < 16; c++)
        if (key[c] == m) key[c] = ~0ULL;
    }
  } else {
    float* W = SM;                        // one 64x64 matrix at a time
    int pb = blk - (24 + 4096);
    int wave = t >> 6, lane = t & 63;
    int pbase = pb * 64 + wave * 16;
    // ---- pass A: Wc = W0a + W0b -> p_c ----
    for (int e = t; e < 4096; e += 256) {
      int o = e & 63, i = e >> 6;         // stride-1 LDS writes
      W[i * 64 + o] = W0[o * 128 + i] + W0[o * 128 + 64 + i];
    }
    __syncthreads();
    for (int it = 0; it < 16; it++) {
      int p = pbase + it;
      const float* xr = x + (size_t)__builtin_amdgcn_readfirstlane(p) * 64;
      float pc = b0[lane];
#pragma unroll
      for (int i = 0; i < 64; i++) pc = fmaf(xr[i], W[i * 64 + lane], pc);
      p_c[(size_t)p * 64 + lane] = pc;
    }
    __syncthreads();                      // WAR: reads done before reload
    // ---- pass B: Wn = W0b -> p_n ----
    for (int e = t; e < 4096; e += 256) {
      int o = e & 63, i = e >> 6;
      W[i * 64 + o] = W0[o * 128 + 64 + i];
    }
    __syncthreads();
    for (int it = 0; it < 16; it++) {
      int p = pbase + it;
      const float* xr = x + (size_t)__builtin_amdgcn_readfirstlane(p) * 64;
      float pn = 0.0f;
#pragma unroll
      for (int i = 0; i < 64; i++) pn = fmaf(xr[i], W[i * 64 + lane], pn);
      p_n[(size_t)p * 64 + lane] = pn;
    }
  }
}

// ---------------------------------------------------------------------------
// layerA — BYTE-IDENTICAL to R20/R21 (passed): layer0 + hidden-0 fused.
// ---------------------------------------------------------------------------
__global__ __launch_bounds__(128) void layerA_kernel(
    const float* __restrict__ p_c, const float* __restrict__ p_n,
    const int* __restrict__ knn_, const u32x4* __restrict__ whi,
    const u32x4* __restrict__ wlo, const float* __restrict__ bh,
    const float* __restrict__ ln_g, const float* __restrict__ ln_b,
    const float* __restrict__ prelu_a, u32* __restrict__ Hout) {
  const int t = threadIdx.x;
  const int wv = t >> 6, l = t & 63;
  const int c = l & 15;
  const int g = l >> 4;
  const int pbase = blockIdx.x * 8 + wv * 4;
  const int b = pbase >> 10;

  u32x4 bhi[4][2], blo[4][2];

  {
    float h[64];
    int p0 = pbase + g;
    int j = knn_[(size_t)p0 * 16 + c];
    const float4* pc4 = reinterpret_cast<const float4*>(p_c + (size_t)p0 * 64);
    const float4* pn4 = reinterpret_cast<const float4*>(p_n + (size_t)((b << 10) + j) * 64);
#pragma unroll
    for (int q = 0; q < 16; q++) {
      float4 a = pc4[q], v = pn4[q];
      h[q * 4 + 0] = a.x - v.x;
      h[q * 4 + 1] = a.y - v.y;
      h[q * 4 + 2] = a.z - v.z;
      h[q * 4 + 3] = a.w - v.w;
    }
    float s = 0.0f, s2 = 0.0f;
#pragma unroll
    for (int o = 0; o < 64; o++) { s += h[o]; s2 += h[o] * h[o]; }
    float mu = s * (1.0f / 64.0f);
    float var = s2 * (1.0f / 64.0f) - mu * mu;
    float inv = rsqrtf(var + LN_EPS);
    float aslope = prelu_a[0];
#pragma unroll
    for (int o = 0; o < 64; o++) {
      float v = ln_g[o] * ((h[o] - mu) * inv) + ln_b[o];
      h[o] = v > 0.0f ? v : aslope * v;
    }
    u32 hpk_hi[32], hpk_lo[32];
#pragma unroll
    for (int w = 0; w < 32; w++) {
      float f0 = h[2 * w], f1 = h[2 * w + 1];
      u32 h0 = rn_hi32(f0);
      u32 h1 = rn_hi32(f1);
      float l0 = f0 - __uint_as_float(h0);
      float l1 = f1 - __uint_as_float(h1);
      hpk_hi[w] = (h0 >> 16) | h1;
      hpk_lo[w] = rn_b16(l0) | (rn_b16(l1) << 16);
    }
#pragma unroll
    for (int nt = 0; nt < 4; nt++) {
      int src = c + 16 * nt;
#pragma unroll
      for (int ks = 0; ks < 2; ks++)
#pragma unroll
        for (int gw = 0; gw < 4; gw++)
#pragma unroll
          for (int j2 = 0; j2 < 4; j2++) {
            u32 th = (u32)__shfl((int)hpk_hi[16 * ks + 4 * gw + j2], src, 64);
            u32 tl = (u32)__shfl((int)hpk_lo[16 * ks + 4 * gw + j2], src, 64);
            if (g == gw) {
              bhi[nt][ks][j2] = th;
              blo[nt][ks][j2] = tl;
            }
          }
    }
  }

  const int li = 0;
  f32x4 bias4[4];
#pragma unroll
  for (int m = 0; m < 4; m++)
    bias4[m] = *(const f32x4*)(bh + li * 64 + 16 * m + 4 * g);

  f32x4 acc[4][4];
#pragma unroll
  for (int m = 0; m < 4; m++)
#pragma unroll
    for (int nt = 0; nt < 4; nt++) acc[m][nt] = bias4[m];

#pragma unroll
  for (int ks = 0; ks < 2; ks++)
#pragma unroll
    for (int m = 0; m < 4; m++) {
      int fi = ((li * 4 + m) * 2 + ks) * 64 + l;
      short8 ah = __builtin_bit_cast(short8, whi[fi]);
      short8 al = __builtin_bit_cast(short8, wlo[fi]);
#pragma unroll
      for (int nt = 0; nt < 4; nt++) {
        short8 bh_ = __builtin_bit_cast(short8, bhi[nt][ks]);
        short8 bl_ = __builtin_bit_cast(short8, blo[nt][ks]);
        acc[m][nt] = __builtin_amdgcn_mfma_f32_16x16x32_bf16(ah, bh_, acc[m][nt], 0, 0, 0);
        acc[m][nt] = __builtin_amdgcn_mfma_f32_16x16x32_bf16(ah, bl_, acc[m][nt], 0, 0, 0);
        acc[m][nt] = __builtin_amdgcn_mfma_f32_16x16x32_bf16(al, bh_, acc[m][nt], 0, 0, 0);
      }
    }

  f32x4 g4[4], b4[4];
#pragma unroll
  for (int m = 0; m < 4; m++) {
    g4[m] = *(const f32x4*)(ln_g + (li + 1) * 64 + 16 * m + 4 * g);
    b4[m] = *(const f32x4*)(ln_b + (li + 1) * 64 + 16 * m + 4 * g);
  }
  float aslope = prelu_a[li + 1];
#pragma unroll
  for (int nt = 0; nt < 4; nt++) {
    float s = 0.0f, s2 = 0.0f;
#pragma unroll
    for (int m = 0; m < 4; m++)
#pragma unroll
      for (int v = 0; v < 4; v++) {
        float x = acc[m][nt][v];
        s += x;
        s2 = fmaf(x, x, s2);
      }
    s += __shfl_xor(s, 16, 64);
    s2 += __shfl_xor(s2, 16, 64);
    s += __shfl_xor(s, 32, 64);
    s2 += __shfl_xor(s2, 32, 64);
    float mu = s * (1.0f / 64.0f);
    float var = s2 * (1.0f / 64.0f) - mu * mu;
    float inv = rsqrtf(var + LN_EPS);
#pragma unroll
    for (int m = 0; m < 4; m++)
#pragma unroll
      for (int v = 0; v < 4; v++) {
        float x = (acc[m][nt][v] - mu) * inv;
        x = g4[m][v] * x + b4[m][v];
        acc[m][nt][v] = x > 0.0f ? x : aslope * x;
      }
  }

#pragma unroll
  for (int nt = 0; nt < 4; nt++) {
    size_t eb = ((size_t)(pbase + nt) * 16 + c) * 32;
#pragma unroll
    for (int m = 0; m < 4; m++) {
      u32x2 v;
      v[0] = rn_b16(acc[m][nt][0]) | (rn_b16(acc[m][nt][1]) << 16);
      v[1] = rn_b16(acc[m][nt][2]) | (rn_b16(acc[m][nt][3]) << 16);
      *(u32x2*)(Hout + eb + 8 * m + 2 * g) = v;
    }
  }
}

// ---------------------------------------------------------------------------
// layer (global path): BYTE-IDENTICAL to R17 (passed). Double-buffered H.
// ---------------------------------------------------------------------------
__global__ __launch_bounds__(128) void layer_kernel(
    const u32* __restrict__ Hin, u32* __restrict__ Hout,
    const u32x4* __restrict__ whi, const u32x4* __restrict__ wlo,
    const float* __restrict__ bh, const float* __restrict__ ln_g,
    const float* __restrict__ ln_b, const float* __restrict__ prelu_a,
    const float* __restrict__ ntr, float* __restrict__ out, int li, int last) {
  const int t = threadIdx.x;
  const int wv = t >> 6, l = t & 63;
  const int c = l & 15;
  const int g = l >> 4;
  const int pbase = blockIdx.x * 8 + wv * 4;
  const int b = pbase >> 10;

  u32x4 bw[4][2];
#pragma unroll
  for (int nt = 0; nt < 4; nt++) {
    size_t eb = ((size_t)(pbase + nt) * 16 + c) * 32;
#pragma unroll
    for (int ks = 0; ks < 2; ks++)
      bw[nt][ks] = *(const u32x4*)(Hin + eb + 16 * ks + 4 * g);
  }

  f32x4 bias4[4];
#pragma unroll
  for (int m = 0; m < 4; m++)
    bias4[m] = *(const f32x4*)(bh + li * 64 + 16 * m + 4 * g);

  f32x4 acc[4][4];  // [m][nt]
#pragma unroll
  for (int m = 0; m < 4; m++)
#pragma unroll
    for (int nt = 0; nt < 4; nt++) acc[m][nt] = bias4[m];

#pragma unroll
  for (int ks = 0; ks < 2; ks++)
#pragma unroll
    for (int m = 0; m < 4; m++) {
      int fi = ((li * 4 + m) * 2 + ks) * 64 + l;
      short8 ah = __builtin_bit_cast(short8, whi[fi]);
      short8 al = __builtin_bit_cast(short8, wlo[fi]);
#pragma unroll
      for (int nt = 0; nt < 4; nt++) {
        short8 bb = __builtin_bit_cast(short8, bw[nt][ks]);
        acc[m][nt] = __builtin_amdgcn_mfma_f32_16x16x32_bf16(ah, bb, acc[m][nt], 0, 0, 0);
        acc[m][nt] = __builtin_amdgcn_mfma_f32_16x16x32_bf16(al, bb, acc[m][nt], 0, 0, 0);
      }
    }

  f32x4 g4[4], b4[4];
#pragma unroll
  for (int m = 0; m < 4; m++) {
    g4[m] = *(const f32x4*)(ln_g + (li + 1) * 64 + 16 * m + 4 * g);
    b4[m] = *(const f32x4*)(ln_b + (li + 1) * 64 + 16 * m + 4 * g);
  }
  float aslope = prelu_a[li + 1];
#pragma unroll
  for (int nt = 0; nt < 4; nt++) {
    float s = 0.0f, s2 = 0.0f;
#pragma unroll
    for (int m = 0; m < 4; m++)
#pragma unroll
      for (int v = 0; v < 4; v++) {
        float x = acc[m][nt][v];
        s += x;
        s2 = fmaf(x, x, s2);
      }
    s += __shfl_xor(s, 16, 64);
    s2 += __shfl_xor(s2, 16, 64);
    s += __shfl_xor(s, 32, 64);
    s2 += __shfl_xor(s2, 32, 64);
    float mu = s * (1.0f / 64.0f);
    float var = s2 * (1.0f / 64.0f) - mu * mu;
    float inv = rsqrtf(var + LN_EPS);
#pragma unroll
    for (int m = 0; m < 4; m++)
#pragma unroll
      for (int v = 0; v < 4; v++) {
        float x = (acc[m][nt][v] - mu) * inv;
        x = g4[m][v] * x + b4[m][v];
        acc[m][nt][v] = x > 0.0f ? x : aslope * x;
      }
  }

  if (!last) {
#pragma unroll
    for (int nt = 0; nt < 4; nt++) {
      size_t eb = ((size_t)(pbase + nt) * 16 + c) * 32;
#pragma unroll
      for (int m = 0; m < 4; m++) {
        u32x2 v;
        v[0] = rn_b16(acc[m][nt][0]) | (rn_b16(acc[m][nt][1]) << 16);
        v[1] = rn_b16(acc[m][nt][2]) | (rn_b16(acc[m][nt][3]) << 16);
        *(u32x2*)(Hout + eb + 8 * m + 2 * g) = v;
      }
    }
  } else {
    float cnt = ntr[b];
    float n_safe = (cnt == 0.0f) ? 1.0f : cnt;
    float rinv = 1.0f / n_safe;
    float msk = ((float)c < cnt) ? 1.0f : 0.0f;
#pragma unroll
    for (int nt = 0; nt < 4; nt++)
#pragma unroll
      for (int m = 0; m < 4; m++) {
        f32x4 r;
#pragma unroll
        for (int v = 0; v < 4; v++) {
          float x = acc[m][nt][v] * msk;
          x += __shfl_xor(x, 1, 64);
          x += __shfl_xor(x, 2, 64);
          x += __shfl_xor(x, 4, 64);
          x += __shfl_xor(x, 8, 64);
          r[v] = x * rinv;
        }
        if (c == 0)
          *(f32x4*)(out + (size_t)(pbase + nt) * 64 + 16 * m + 4 * g) = r;
      }
  }
}

// ---------------------------------------------------------------------------
// mlp_mfma3 — BYTE-EXACT R11/R13 kernel (passed 3x). FALLBACK path.
// ---------------------------------------------------------------------------
__global__ __launch_bounds__(128) void mlp_mfma3_kernel(
    const float* __restrict__ p_c, const float* __restrict__ p_n,
    const int* __restrict__ knn_, const u32x4* __restrict__ whi,
    const u32x4* __restrict__ wlo, const float* __restrict__ bh,
    const float* __restrict__ ln_g, const float* __restrict__ ln_b,
    const float* __restrict__ prelu_a, const float* __restrict__ ntr,
    float* __restrict__ out) {
  const int t = threadIdx.x;
  const int wv = t >> 6, l = t & 63;
  const int c = l & 15;
  const int g = l >> 4;
  const int pbase = blockIdx.x * 8 + wv * 4;
  const int b = pbase >> 10;

  u32x4 bhi[4][2], blo[4][2];

  {
    float h[64];
    int p0 = pbase + g;
    int j = knn_[(size_t)p0 * 16 + c];
    const float4* pc4 = reinterpret_cast<const float4*>(p_c + (size_t)p0 * 64);
    const float4* pn4 = reinterpret_cast<const float4*>(p_n + (size_t)((b << 10) + j) * 64);
#pragma unroll
    for (int q = 0; q < 16; q++) {
      float4 a = pc4[q], v = pn4[q];
      h[q * 4 + 0] = a.x - v.x;
      h[q * 4 + 1] = a.y - v.y;
      h[q * 4 + 2] = a.z - v.z;
      h[q * 4 + 3] = a.w - v.w;
    }
    float s = 0.0f, s2 = 0.0f;
#pragma unroll
    for (int o = 0; o < 64; o++) { s += h[o]; s2 += h[o] * h[o]; }
    float mu = s * (1.0f / 64.0f);
    float var = s2 * (1.0f / 64.0f) - mu * mu;
    float inv = rsqrtf(var + LN_EPS);
    float aslope = prelu_a[0];
#pragma unroll
    for (int o = 0; o < 64; o++) {
      float v = ln_g[o] * ((h[o] - mu) * inv) + ln_b[o];
      h[o] = v > 0.0f ? v : aslope * v;
    }
    u32 hpk_hi[32], hpk_lo[32];
#pragma unroll
    for (int w = 0; w < 32; w++) {
      float f0 = h[2 * w], f1 = h[2 * w + 1];
      u32 h0 = rn_hi32(f0);
      u32 h1 = rn_hi32(f1);
      float l0 = f0 - __uint_as_float(h0);
      float l1 = f1 - __uint_as_float(h1);
      hpk_hi[w] = (h0 >> 16) | h1;
      hpk_lo[w] = rn_b16(l0) | (rn_b16(l1) << 16);
    }
#pragma unroll
    for (int nt = 0; nt < 4; nt++) {
      int src = c + 16 * nt;
#pragma unroll
      for (int ks = 0; ks < 2; ks++)
#pragma unroll
        for (int gw = 0; gw < 4; gw++)
#pragma unroll
          for (int j2 = 0; j2 < 4; j2++) {
            u32 th = (u32)__shfl((int)hpk_hi[16 * ks + 4 * gw + j2], src, 64);
            u32 tl = (u32)__shfl((int)hpk_lo[16 * ks + 4 * gw + j2], src, 64);
            if (g == gw) {
              bhi[nt][ks][j2] = th;
              blo[nt][ks][j2] = tl;
            }
          }
    }
  }

  float cnt = ntr[b];

#pragma unroll 1
  for (int li = 0; li < 4; li++) {
    f32x4 bias4[4];
#pragma unroll
    for (int m = 0; m < 4; m++)
      bias4[m] = *(const f32x4*)(bh + li * 64 + 16 * m + 4 * g);

    f32x4 acc[4][4];
#pragma unroll
    for (int m = 0; m < 4; m++)
#pragma unroll
      for (int nt = 0; nt < 4; nt++) acc[m][nt] = bias4[m];

#pragma unroll
    for (int ks = 0; ks < 2; ks++)
#pragma unroll
      for (int m = 0; m < 4; m++) {
        int fi = ((li * 4 + m) * 2 + ks) * 64 + l;
        short8 ah = __builtin_bit_cast(short8, whi[fi]);
        short8 al = __builtin_bit_cast(short8, wlo[fi]);
#pragma unroll
        for (int nt = 0; nt < 4; nt++) {
          short8 bh_ = __builtin_bit_cast(short8, bhi[nt][ks]);
          short8 bl_ = __builtin_bit_cast(short8, blo[nt][ks]);
          acc[m][nt] = __builtin_amdgcn_mfma_f32_16x16x32_bf16(ah, bh_, acc[m][nt], 0, 0, 0);
          acc[m][nt] = __builtin_amdgcn_mfma_f32_16x16x32_bf16(ah, bl_, acc[m][nt], 0, 0, 0);
          acc[m][nt] = __builtin_amdgcn_mfma_f32_16x16x32_bf16(al, bh_, acc[m][nt], 0, 0, 0);
        }
      }

    f32x4 g4[4], b4[4];
#pragma unroll
    for (int m = 0; m < 4; m++) {
      g4[m] = *(const f32x4*)(ln_g + (li + 1) * 64 + 16 * m + 4 * g);
      b4[m] = *(const f32x4*)(ln_b + (li + 1) * 64 + 16 * m + 4 * g);
    }
    float aslope = prelu_a[li + 1];
#pragma unroll
    for (int nt = 0; nt < 4; nt++) {
      float s = 0.0f, s2 = 0.0f;
#pragma unroll
      for (int m = 0; m < 4; m++)
#pragma unroll
        for (int v = 0; v < 4; v++) {
          float x = acc[m][nt][v];
          s += x;
          s2 = fmaf(x, x, s2);
        }
      s += __shfl_xor(s, 16, 64);
      s2 += __shfl_xor(s2, 16, 64);
      s += __shfl_xor(s, 32, 64);
      s2 += __shfl_xor(s2, 32, 64);
      float mu = s * (1.0f / 64.0f);
      float var = s2 * (1.0f / 64.0f) - mu * mu;
      float inv = rsqrtf(var + LN_EPS);
#pragma unroll
      for (int m = 0; m < 4; m++)
#pragma unroll
        for (int v = 0; v < 4; v++) {
          float x = (acc[m][nt][v] - mu) * inv;
          x = g4[m][v] * x + b4[m][v];
          acc[m][nt][v] = x > 0.0f ? x : aslope * x;
        }
    }

    if (li < 3) {
      float h[64];
#pragma unroll
      for (int o = 0; o < 64; o++) {
        int srcl = c + 16 * ((o >> 2) & 3);
#pragma unroll
        for (int ntp = 0; ntp < 4; ntp++) {
          float tv = __shfl(acc[o >> 4][ntp][o & 3], srcl, 64);
          if (g == ntp) h[o] = tv;
        }
      }
      u32 hpk_hi[32], hpk_lo[32];
#pragma unroll
      for (int w = 0; w < 32; w++) {
        float f0 = h[2 * w], f1 = h[2 * w + 1];
        u32 h0 = rn_hi32(f0);
        u32 h1 = rn_hi32(f1);
        float l0 = f0 - __uint_as_float(h0);
        float l1 = f1 - __uint_as_float(h1);
        hpk_hi[w] = (h0 >> 16) | h1;
        hpk_lo[w] = rn_b16(l0) | (rn_b16(l1) << 16);
      }
#pragma unroll
      for (int nt = 0; nt < 4; nt++) {
        int src = c + 16 * nt;
#pragma unroll
        for (int ks = 0; ks < 2; ks++)
#pragma unroll
          for (int gw = 0; gw < 4; gw++)
#pragma unroll
            for (int j2 = 0; j2 < 4; j2++) {
              u32 th = (u32)__shfl((int)hpk_hi[16 * ks + 4 * gw + j2], src, 64);
              u32 tl = (u32)__shfl((int)hpk_lo[16 * ks + 4 * gw + j2], src, 64);
              if (g == gw) {
                bhi[nt][ks][j2] = th;
                blo[nt][ks][j2] = tl;
              }
            }
      }
    } else {
      float n_safe = (cnt == 0.0f) ? 1.0f : cnt;
      float rinv = 1.0f / n_safe;
      float msk = ((float)c < cnt) ? 1.0f : 0.0f;
#pragma unroll
      for (int nt = 0; nt < 4; nt++)
#pragma unroll
        for (int m = 0; m < 4; m++) {
          f32x4 r;
#pragma unroll
          for (int v = 0; v < 4; v++) {
            float x = acc[m][nt][v] * msk;
            x += __shfl_xor(x, 1, 64);
            x += __shfl_xor(x, 2, 64);
            x += __shfl_xor(x, 4, 64);
            x += __shfl_xor(x, 8, 64);
            r[v] = x * rinv;
          }
          if (c == 0)
            *(f32x4*)(out + (size_t)(pbase + nt) * 64 + 16 * m + 4 * g) = r;
        }
    }
  }
}

// ---------------------------------------------------------------------------
extern "C" void kernel_launch(void* const* d_in, const int* in_sizes, int n_in,
                              void* d_out, int out_size, void* d_ws, size_t ws_size,
                              hipStream_t stream) {
  const float* points  = (const float*)d_in[0];
  const float* x       = (const float*)d_in[1];
  const int*   mask    = (const int*)d_in[2];
  const float* W0      = (const float*)d_in[3];
  const float* b0      = (const float*)d_in[4];
  const float* Wh      = (const float*)d_in[5];
  const float* bh      = (const float*)d_in[6];
  const float* ln_g    = (const float*)d_in[7];
  const float* ln_b    = (const float*)d_in[8];
  const float* prelu_a = (const float*)d_in[9];
  float* out = (float*)d_out;

  char* ws = (char*)d_ws;
  int*   knn  = (int*)ws;                                    // 1 MB
  float* p_c  = (float*)(ws + (1 << 20));                    // 4 MB
  float* p_n  = (float*)(ws + (1 << 20) + (4 << 20));        // 4 MB
  u32x4* whi  = (u32x4*)(ws + (9 << 20));                    // 32 KB
  u32x4* wlo  = (u32x4*)(ws + (9 << 20) + (32 << 10));       // 32 KB
  float* ntr  = (float*)(ws + (9 << 20) + (64 << 10));       // 64 B
  u32*   H0   = (u32*)(ws + ((size_t)10 << 20));             // 32 MB
  u32*   H1   = (u32*)(ws + ((size_t)42 << 20));             // 32 MB

  front_kernel<<<24 + 4096 + 256, 256, 0, stream>>>(
      Wh, whi, wlo, mask, ntr, points, knn, x, W0, b0, p_c, p_n);

  if (ws_size >= ((size_t)74 << 20)) {
    // global-transport path: layerA (layer0 + hidden-0 fused) + 3 layers
    layerA_kernel<<<2048, 128, 0, stream>>>(p_c, p_n, knn, whi, wlo, bh,
                                            ln_g, ln_b, prelu_a, H0);
    layer_kernel<<<2048, 128, 0, stream>>>(H0, H1, whi, wlo, bh, ln_g, ln_b,
                                           prelu_a, ntr, out, 1, 0);
    layer_kernel<<<2048, 128, 0, stream>>>(H1, H0, whi, wlo, bh, ln_g, ln_b,
                                           prelu_a, ntr, out, 2, 0);
    layer_kernel<<<2048, 128, 0, stream>>>(H0, H1, whi, wlo, bh, ln_g, ln_b,
                                           prelu_a, ntr, out, 3, 1);
  } else {
    // fallback: byte-exact R13 mlp (passed 3x)
    mlp_mfma3_kernel<<<2048, 128, 0, stream>>>(p_c, p_n, knn, whi, wlo, bh,
                                               ln_g, ln_b, prelu_a, ntr, out);
  }
}

// Round 24
// 187.556 us; speedup vs baseline: 1.0337x; 1.0058x over previous
//
#include <hip/hip_runtime.h>
#include <hip/hip_bf16.h>
#include <math.h>

#define N_ 1024
#define KNN_K 16
#define LN_EPS 1e-5f

typedef unsigned long long u64;
typedef unsigned int u32;
typedef __attribute__((ext_vector_type(4))) float f32x4;
typedef __attribute__((ext_vector_type(8))) short short8;
typedef __attribute__((ext_vector_type(2))) unsigned int u32x2;
typedef __attribute__((ext_vector_type(4))) unsigned int u32x4;

// Round-to-nearest-even bf16 helpers.
__device__ __forceinline__ u32 rn_hi32(float v) {  // bf16 bits in high half
  u32 u = __float_as_uint(v);
  return (u + 0x7FFFu + ((u >> 16) & 1u)) & 0xFFFF0000u;
}
__device__ __forceinline__ u32 rn_b16(float v) {   // bf16 bits as 16-bit value
  u32 u = __float_as_uint(v);
  return (u + 0x7FFFu + ((u >> 16) & 1u)) >> 16;
}
__device__ __forceinline__ u64 umin64(u64 a, u64 b) { return a < b ? a : b; }

// ---------------------------------------------------------------------------
// front: R21/R23 form (passed twice) with ONE isolated change: knn consume
// uses the winner (lane,slot) DECODED from the min key's index bits
// (wl=m&63, wc=(m>>6)&15 — exact: j=lane+64c encodes both; winner is never a
// consumed slot). Correctness of this decode is HW-proven (R22 passed with
// it). Saves ~16 u64 cmp+sel per round in the issue-bound knn loop.
// ---------------------------------------------------------------------------
__global__ __launch_bounds__(256) void front_kernel(
    const float* __restrict__ Wh, u32x4* __restrict__ whi,
    u32x4* __restrict__ wlo, const int* __restrict__ mask,
    float* __restrict__ ntr, const float* __restrict__ points,
    int* __restrict__ knn, const float* __restrict__ x,
    const float* __restrict__ W0, const float* __restrict__ b0,
    float* __restrict__ p_c, float* __restrict__ p_n) {
  __shared__ float SM[4096];              // 16 KiB
  const int blk = blockIdx.x;
  const int t = threadIdx.x;

  if (blk < 8) {
    int idx = blk * 256 + t;
    int lane = idx & 63;
    int ks = (idx >> 6) & 1;
    int m = (idx >> 7) & 3;
    int li = idx >> 9;
    int o = 16 * m + (lane & 15);
    int k0 = 32 * ks + 8 * (lane >> 4);
    const float* w = Wh + li * 4096 + o * 64 + k0;
    u32x4 hi, lo;
#pragma unroll
    for (int j = 0; j < 4; j++) {
      float f0 = w[2 * j], f1 = w[2 * j + 1];
      u32 h0 = rn_hi32(f0);
      u32 h1 = rn_hi32(f1);
      float l0 = f0 - __uint_as_float(h0);
      float l1 = f1 - __uint_as_float(h1);
      hi[j] = (h0 >> 16) | h1;
      lo[j] = rn_b16(l0) | (rn_b16(l1) << 16);
    }
    int fi = ((li * 4 + m) * 2 + ks) * 64 + lane;
    whi[fi] = hi;
    wlo[fi] = lo;
  } else if (blk < 24) {
    int b = blk - 8;
    int s = 0;
    for (int e = t; e < N_; e += 256) s += mask[b * N_ + e];
    for (int off = 32; off; off >>= 1) s += __shfl_xor(s, off, 64);
    int* accI = (int*)SM;
    int wave = t >> 6, lane = t & 63;
    if (lane == 0) accI[wave] = s;
    __syncthreads();
    if (t == 0) ntr[b] = (float)(accI[0] + accI[1] + accI[2] + accI[3]);
  } else if (blk < 24 + 4096) {
#pragma clang fp contract(off)
    float* px = SM;
    float* py = SM + 1024;
    float* pz = SM + 2048;
    float* minf = SM + 3072;
    int kb = blk - 24;
    int b = kb >> 8;
    int qbase = (kb & 255) << 2;
    for (int j = t; j < N_; j += 256) {
      const float* p = points + ((size_t)(b * N_ + j)) * 3;
      px[j] = p[0];
      py[j] = p[1];
      pz[j] = p[2];
      minf[j] = mask[b * N_ + j] ? 0.0f : __builtin_inff();
    }
    __syncthreads();
    int wave = t >> 6, lane = t & 63;
    int n = qbase + wave;
    float qx = px[n], qy = py[n], qz = pz[n];
    u64 key[16];
#pragma unroll
    for (int c = 0; c < 16; c++) {
      int j = lane + (c << 6);
      float dx = qx - px[j];
      float dy = qy - py[j];
      float dz = qz - pz[j];
      float d2 = dx * dx + dy * dy + dz * dz;
      d2 = d2 + minf[j];
      key[c] = ((u64)__float_as_uint(d2) << 32) | (u32)j;
    }
    int* dst = knn + ((size_t)(b * N_ + n)) * KNN_K;
    for (int s = 0; s < 16; s++) {
      // depth-4 tree min over the 16 local keys (exact; min associative)
      u64 a0 = umin64(key[0], key[1]);
      u64 a1 = umin64(key[2], key[3]);
      u64 a2 = umin64(key[4], key[5]);
      u64 a3 = umin64(key[6], key[7]);
      u64 a4 = umin64(key[8], key[9]);
      u64 a5 = umin64(key[10], key[11]);
      u64 a6 = umin64(key[12], key[13]);
      u64 a7 = umin64(key[14], key[15]);
      u64 b0_ = umin64(a0, a1);
      u64 b1_ = umin64(a2, a3);
      u64 b2_ = umin64(a4, a5);
      u64 b3_ = umin64(a6, a7);
      u64 m = umin64(umin64(b0_, b1_), umin64(b2_, b3_));
#pragma unroll
      for (int off = 32; off; off >>= 1) {
        u64 o = __shfl_xor(m, off, 64);
        if (o < m) m = o;
      }
      if (lane == 0) dst[s] = (int)(m & 0xFFFFFFFFu);
      // consume via decoded winner (R22-proven): j=lane+64c -> wl, wc
      int wl = (int)(m & 63u), wc = (int)((m >> 6) & 15u);
#pragma unroll
      for (int c = 0; c < 16; c++)
        if (lane == wl && c == wc) key[c] = ~0ULL;
    }
  } else {
    float* W = SM;                        // one 64x64 matrix at a time
    int pb = blk - (24 + 4096);
    int wave = t >> 6, lane = t & 63;
    int pbase = pb * 64 + wave * 16;
    // ---- pass A: Wc = W0a + W0b -> p_c ----
    for (int e = t; e < 4096; e += 256) {
      int o = e & 63, i = e >> 6;         // stride-1 LDS writes
      W[i * 64 + o] = W0[o * 128 + i] + W0[o * 128 + 64 + i];
    }
    __syncthreads();
    for (int it = 0; it < 16; it++) {
      int p = pbase + it;
      const float* xr = x + (size_t)__builtin_amdgcn_readfirstlane(p) * 64;
      float pc = b0[lane];
#pragma unroll
      for (int i = 0; i < 64; i++) pc = fmaf(xr[i], W[i * 64 + lane], pc);
      p_c[(size_t)p * 64 + lane] = pc;
    }
    __syncthreads();                      // WAR: reads done before reload
    // ---- pass B: Wn = W0b -> p_n ----
    for (int e = t; e < 4096; e += 256) {
      int o = e & 63, i = e >> 6;
      W[i * 64 + o] = W0[o * 128 + 64 + i];
    }
    __syncthreads();
    for (int it = 0; it < 16; it++) {
      int p = pbase + it;
      const float* xr = x + (size_t)__builtin_amdgcn_readfirstlane(p) * 64;
      float pn = 0.0f;
#pragma unroll
      for (int i = 0; i < 64; i++) pn = fmaf(xr[i], W[i * 64 + lane], pn);
      p_n[(size_t)p * 64 + lane] = pn;
    }
  }
}

// ---------------------------------------------------------------------------
// layerA — BYTE-IDENTICAL to R20/R21/R23 (passed): layer0 + hidden-0 fused.
// ---------------------------------------------------------------------------
__global__ __launch_bounds__(128) void layerA_kernel(
    const float* __restrict__ p_c, const float* __restrict__ p_n,
    const int* __restrict__ knn_, const u32x4* __restrict__ whi,
    const u32x4* __restrict__ wlo, const float* __restrict__ bh,
    const float* __restrict__ ln_g, const float* __restrict__ ln_b,
    const float* __restrict__ prelu_a, u32* __restrict__ Hout) {
  const int t = threadIdx.x;
  const int wv = t >> 6, l = t & 63;
  const int c = l & 15;
  const int g = l >> 4;
  const int pbase = blockIdx.x * 8 + wv * 4;
  const int b = pbase >> 10;

  u32x4 bhi[4][2], blo[4][2];

  {
    float h[64];
    int p0 = pbase + g;
    int j = knn_[(size_t)p0 * 16 + c];
    const float4* pc4 = reinterpret_cast<const float4*>(p_c + (size_t)p0 * 64);
    const float4* pn4 = reinterpret_cast<const float4*>(p_n + (size_t)((b << 10) + j) * 64);
#pragma unroll
    for (int q = 0; q < 16; q++) {
      float4 a = pc4[q], v = pn4[q];
      h[q * 4 + 0] = a.x - v.x;
      h[q * 4 + 1] = a.y - v.y;
      h[q * 4 + 2] = a.z - v.z;
      h[q * 4 + 3] = a.w - v.w;
    }
    float s = 0.0f, s2 = 0.0f;
#pragma unroll
    for (int o = 0; o < 64; o++) { s += h[o]; s2 += h[o] * h[o]; }
    float mu = s * (1.0f / 64.0f);
    float var = s2 * (1.0f / 64.0f) - mu * mu;
    float inv = rsqrtf(var + LN_EPS);
    float aslope = prelu_a[0];
#pragma unroll
    for (int o = 0; o < 64; o++) {
      float v = ln_g[o] * ((h[o] - mu) * inv) + ln_b[o];
      h[o] = v > 0.0f ? v : aslope * v;
    }
    u32 hpk_hi[32], hpk_lo[32];
#pragma unroll
    for (int w = 0; w < 32; w++) {
      float f0 = h[2 * w], f1 = h[2 * w + 1];
      u32 h0 = rn_hi32(f0);
      u32 h1 = rn_hi32(f1);
      float l0 = f0 - __uint_as_float(h0);
      float l1 = f1 - __uint_as_float(h1);
      hpk_hi[w] = (h0 >> 16) | h1;
      hpk_lo[w] = rn_b16(l0) | (rn_b16(l1) << 16);
    }
#pragma unroll
    for (int nt = 0; nt < 4; nt++) {
      int src = c + 16 * nt;
#pragma unroll
      for (int ks = 0; ks < 2; ks++)
#pragma unroll
        for (int gw = 0; gw < 4; gw++)
#pragma unroll
          for (int j2 = 0; j2 < 4; j2++) {
            u32 th = (u32)__shfl((int)hpk_hi[16 * ks + 4 * gw + j2], src, 64);
            u32 tl = (u32)__shfl((int)hpk_lo[16 * ks + 4 * gw + j2], src, 64);
            if (g == gw) {
              bhi[nt][ks][j2] = th;
              blo[nt][ks][j2] = tl;
            }
          }
    }
  }

  const int li = 0;
  f32x4 bias4[4];
#pragma unroll
  for (int m = 0; m < 4; m++)
    bias4[m] = *(const f32x4*)(bh + li * 64 + 16 * m + 4 * g);

  f32x4 acc[4][4];
#pragma unroll
  for (int m = 0; m < 4; m++)
#pragma unroll
    for (int nt = 0; nt < 4; nt++) acc[m][nt] = bias4[m];

#pragma unroll
  for (int ks = 0; ks < 2; ks++)
#pragma unroll
    for (int m = 0; m < 4; m++) {
      int fi = ((li * 4 + m) * 2 + ks) * 64 + l;
      short8 ah = __builtin_bit_cast(short8, whi[fi]);
      short8 al = __builtin_bit_cast(short8, wlo[fi]);
#pragma unroll
      for (int nt = 0; nt < 4; nt++) {
        short8 bh_ = __builtin_bit_cast(short8, bhi[nt][ks]);
        short8 bl_ = __builtin_bit_cast(short8, blo[nt][ks]);
        acc[m][nt] = __builtin_amdgcn_mfma_f32_16x16x32_bf16(ah, bh_, acc[m][nt], 0, 0, 0);
        acc[m][nt] = __builtin_amdgcn_mfma_f32_16x16x32_bf16(ah, bl_, acc[m][nt], 0, 0, 0);
        acc[m][nt] = __builtin_amdgcn_mfma_f32_16x16x32_bf16(al, bh_, acc[m][nt], 0, 0, 0);
      }
    }

  f32x4 g4[4], b4[4];
#pragma unroll
  for (int m = 0; m < 4; m++) {
    g4[m] = *(const f32x4*)(ln_g + (li + 1) * 64 + 16 * m + 4 * g);
    b4[m] = *(const f32x4*)(ln_b + (li + 1) * 64 + 16 * m + 4 * g);
  }
  float aslope = prelu_a[li + 1];
#pragma unroll
  for (int nt = 0; nt < 4; nt++) {
    float s = 0.0f, s2 = 0.0f;
#pragma unroll
    for (int m = 0; m < 4; m++)
#pragma unroll
      for (int v = 0; v < 4; v++) {
        float x = acc[m][nt][v];
        s += x;
        s2 = fmaf(x, x, s2);
      }
    s += __shfl_xor(s, 16, 64);
    s2 += __shfl_xor(s2, 16, 64);
    s += __shfl_xor(s, 32, 64);
    s2 += __shfl_xor(s2, 32, 64);
    float mu = s * (1.0f / 64.0f);
    float var = s2 * (1.0f / 64.0f) - mu * mu;
    float inv = rsqrtf(var + LN_EPS);
#pragma unroll
    for (int m = 0; m < 4; m++)
#pragma unroll
      for (int v = 0; v < 4; v++) {
        float x = (acc[m][nt][v] - mu) * inv;
        x = g4[m][v] * x + b4[m][v];
        acc[m][nt][v] = x > 0.0f ? x : aslope * x;
      }
  }

#pragma unroll
  for (int nt = 0; nt < 4; nt++) {
    size_t eb = ((size_t)(pbase + nt) * 16 + c) * 32;
#pragma unroll
    for (int m = 0; m < 4; m++) {
      u32x2 v;
      v[0] = rn_b16(acc[m][nt][0]) | (rn_b16(acc[m][nt][1]) << 16);
      v[1] = rn_b16(acc[m][nt][2]) | (rn_b16(acc[m][nt][3]) << 16);
      *(u32x2*)(Hout + eb + 8 * m + 2 * g) = v;
    }
  }
}

// ---------------------------------------------------------------------------
// layer (global path): BYTE-IDENTICAL to R17 (passed). Double-buffered H.
// ---------------------------------------------------------------------------
__global__ __launch_bounds__(128) void layer_kernel(
    const u32* __restrict__ Hin, u32* __restrict__ Hout,
    const u32x4* __restrict__ whi, const u32x4* __restrict__ wlo,
    const float* __restrict__ bh, const float* __restrict__ ln_g,
    const float* __restrict__ ln_b, const float* __restrict__ prelu_a,
    const float* __restrict__ ntr, float* __restrict__ out, int li, int last) {
  const int t = threadIdx.x;
  const int wv = t >> 6, l = t & 63;
  const int c = l & 15;
  const int g = l >> 4;
  const int pbase = blockIdx.x * 8 + wv * 4;
  const int b = pbase >> 10;

  u32x4 bw[4][2];
#pragma unroll
  for (int nt = 0; nt < 4; nt++) {
    size_t eb = ((size_t)(pbase + nt) * 16 + c) * 32;
#pragma unroll
    for (int ks = 0; ks < 2; ks++)
      bw[nt][ks] = *(const u32x4*)(Hin + eb + 16 * ks + 4 * g);
  }

  f32x4 bias4[4];
#pragma unroll
  for (int m = 0; m < 4; m++)
    bias4[m] = *(const f32x4*)(bh + li * 64 + 16 * m + 4 * g);

  f32x4 acc[4][4];  // [m][nt]
#pragma unroll
  for (int m = 0; m < 4; m++)
#pragma unroll
    for (int nt = 0; nt < 4; nt++) acc[m][nt] = bias4[m];

#pragma unroll
  for (int ks = 0; ks < 2; ks++)
#pragma unroll
    for (int m = 0; m < 4; m++) {
      int fi = ((li * 4 + m) * 2 + ks) * 64 + l;
      short8 ah = __builtin_bit_cast(short8, whi[fi]);
      short8 al = __builtin_bit_cast(short8, wlo[fi]);
#pragma unroll
      for (int nt = 0; nt < 4; nt++) {
        short8 bb = __builtin_bit_cast(short8, bw[nt][ks]);
        acc[m][nt] = __builtin_amdgcn_mfma_f32_16x16x32_bf16(ah, bb, acc[m][nt], 0, 0, 0);
        acc[m][nt] = __builtin_amdgcn_mfma_f32_16x16x32_bf16(al, bb, acc[m][nt], 0, 0, 0);
      }
    }

  f32x4 g4[4], b4[4];
#pragma unroll
  for (int m = 0; m < 4; m++) {
    g4[m] = *(const f32x4*)(ln_g + (li + 1) * 64 + 16 * m + 4 * g);
    b4[m] = *(const f32x4*)(ln_b + (li + 1) * 64 + 16 * m + 4 * g);
  }
  float aslope = prelu_a[li + 1];
#pragma unroll
  for (int nt = 0; nt < 4; nt++) {
    float s = 0.0f, s2 = 0.0f;
#pragma unroll
    for (int m = 0; m < 4; m++)
#pragma unroll
      for (int v = 0; v < 4; v++) {
        float x = acc[m][nt][v];
        s += x;
        s2 = fmaf(x, x, s2);
      }
    s += __shfl_xor(s, 16, 64);
    s2 += __shfl_xor(s2, 16, 64);
    s += __shfl_xor(s, 32, 64);
    s2 += __shfl_xor(s2, 32, 64);
    float mu = s * (1.0f / 64.0f);
    float var = s2 * (1.0f / 64.0f) - mu * mu;
    float inv = rsqrtf(var + LN_EPS);
#pragma unroll
    for (int m = 0; m < 4; m++)
#pragma unroll
      for (int v = 0; v < 4; v++) {
        float x = (acc[m][nt][v] - mu) * inv;
        x = g4[m][v] * x + b4[m][v];
        acc[m][nt][v] = x > 0.0f ? x : aslope * x;
      }
  }

  if (!last) {
#pragma unroll
    for (int nt = 0; nt < 4; nt++) {
      size_t eb = ((size_t)(pbase + nt) * 16 + c) * 32;
#pragma unroll
      for (int m = 0; m < 4; m++) {
        u32x2 v;
        v[0] = rn_b16(acc[m][nt][0]) | (rn_b16(acc[m][nt][1]) << 16);
        v[1] = rn_b16(acc[m][nt][2]) | (rn_b16(acc[m][nt][3]) << 16);
        *(u32x2*)(Hout + eb + 8 * m + 2 * g) = v;
      }
    }
  } else {
    float cnt = ntr[b];
    float n_safe = (cnt == 0.0f) ? 1.0f : cnt;
    float rinv = 1.0f / n_safe;
    float msk = ((float)c < cnt) ? 1.0f : 0.0f;
#pragma unroll
    for (int nt = 0; nt < 4; nt++)
#pragma unroll
      for (int m = 0; m < 4; m++) {
        f32x4 r;
#pragma unroll
        for (int v = 0; v < 4; v++) {
          float x = acc[m][nt][v] * msk;
          x += __shfl_xor(x, 1, 64);
          x += __shfl_xor(x, 2, 64);
          x += __shfl_xor(x, 4, 64);
          x += __shfl_xor(x, 8, 64);
          r[v] = x * rinv;
        }
        if (c == 0)
          *(f32x4*)(out + (size_t)(pbase + nt) * 64 + 16 * m + 4 * g) = r;
      }
  }
}

// ---------------------------------------------------------------------------
// mlp_mfma3 — BYTE-EXACT R11/R13 kernel (passed 3x). FALLBACK path.
// ---------------------------------------------------------------------------
__global__ __launch_bounds__(128) void mlp_mfma3_kernel(
    const float* __restrict__ p_c, const float* __restrict__ p_n,
    const int* __restrict__ knn_, const u32x4* __restrict__ whi,
    const u32x4* __restrict__ wlo, const float* __restrict__ bh,
    const float* __restrict__ ln_g, const float* __restrict__ ln_b,
    const float* __restrict__ prelu_a, const float* __restrict__ ntr,
    float* __restrict__ out) {
  const int t = threadIdx.x;
  const int wv = t >> 6, l = t & 63;
  const int c = l & 15;
  const int g = l >> 4;
  const int pbase = blockIdx.x * 8 + wv * 4;
  const int b = pbase >> 10;

  u32x4 bhi[4][2], blo[4][2];

  {
    float h[64];
    int p0 = pbase + g;
    int j = knn_[(size_t)p0 * 16 + c];
    const float4* pc4 = reinterpret_cast<const float4*>(p_c + (size_t)p0 * 64);
    const float4* pn4 = reinterpret_cast<const float4*>(p_n + (size_t)((b << 10) + j) * 64);
#pragma unroll
    for (int q = 0; q < 16; q++) {
      float4 a = pc4[q], v = pn4[q];
      h[q * 4 + 0] = a.x - v.x;
      h[q * 4 + 1] = a.y - v.y;
      h[q * 4 + 2] = a.z - v.z;
      h[q * 4 + 3] = a.w - v.w;
    }
    float s = 0.0f, s2 = 0.0f;
#pragma unroll
    for (int o = 0; o < 64; o++) { s += h[o]; s2 += h[o] * h[o]; }
    float mu = s * (1.0f / 64.0f);
    float var = s2 * (1.0f / 64.0f) - mu * mu;
    float inv = rsqrtf(var + LN_EPS);
    float aslope = prelu_a[0];
#pragma unroll
    for (int o = 0; o < 64; o++) {
      float v = ln_g[o] * ((h[o] - mu) * inv) + ln_b[o];
      h[o] = v > 0.0f ? v : aslope * v;
    }
    u32 hpk_hi[32], hpk_lo[32];
#pragma unroll
    for (int w = 0; w < 32; w++) {
      float f0 = h[2 * w], f1 = h[2 * w + 1];
      u32 h0 = rn_hi32(f0);
      u32 h1 = rn_hi32(f1);
      float l0 = f0 - __uint_as_float(h0);
      float l1 = f1 - __uint_as_float(h1);
      hpk_hi[w] = (h0 >> 16) | h1;
      hpk_lo[w] = rn_b16(l0) | (rn_b16(l1) << 16);
    }
#pragma unroll
    for (int nt = 0; nt < 4; nt++) {
      int src = c + 16 * nt;
#pragma unroll
      for (int ks = 0; ks < 2; ks++)
#pragma unroll
        for (int gw = 0; gw < 4; gw++)
#pragma unroll
          for (int j2 = 0; j2 < 4; j2++) {
            u32 th = (u32)__shfl((int)hpk_hi[16 * ks + 4 * gw + j2], src, 64);
            u32 tl = (u32)__shfl((int)hpk_lo[16 * ks + 4 * gw + j2], src, 64);
            if (g == gw) {
              bhi[nt][ks][j2] = th;
              blo[nt][ks][j2] = tl;
            }
          }
    }
  }

  float cnt = ntr[b];

#pragma unroll 1
  for (int li = 0; li < 4; li++) {
    f32x4 bias4[4];
#pragma unroll
    for (int m = 0; m < 4; m++)
      bias4[m] = *(const f32x4*)(bh + li * 64 + 16 * m + 4 * g);

    f32x4 acc[4][4];
#pragma unroll
    for (int m = 0; m < 4; m++)
#pragma unroll
      for (int nt = 0; nt < 4; nt++) acc[m][nt] = bias4[m];

#pragma unroll
    for (int ks = 0; ks < 2; ks++)
#pragma unroll
      for (int m = 0; m < 4; m++) {
        int fi = ((li * 4 + m) * 2 + ks) * 64 + l;
        short8 ah = __builtin_bit_cast(short8, whi[fi]);
        short8 al = __builtin_bit_cast(short8, wlo[fi]);
#pragma unroll
        for (int nt = 0; nt < 4; nt++) {
          short8 bh_ = __builtin_bit_cast(short8, bhi[nt][ks]);
          short8 bl_ = __builtin_bit_cast(short8, blo[nt][ks]);
          acc[m][nt] = __builtin_amdgcn_mfma_f32_16x16x32_bf16(ah, bh_, acc[m][nt], 0, 0, 0);
          acc[m][nt] = __builtin_amdgcn_mfma_f32_16x16x32_bf16(ah, bl_, acc[m][nt], 0, 0, 0);
          acc[m][nt] = __builtin_amdgcn_mfma_f32_16x16x32_bf16(al, bh_, acc[m][nt], 0, 0, 0);
        }
      }

    f32x4 g4[4], b4[4];
#pragma unroll
    for (int m = 0; m < 4; m++) {
      g4[m] = *(const f32x4*)(ln_g + (li + 1) * 64 + 16 * m + 4 * g);
      b4[m] = *(const f32x4*)(ln_b + (li + 1) * 64 + 16 * m + 4 * g);
    }
    float aslope = prelu_a[li + 1];
#pragma unroll
    for (int nt = 0; nt < 4; nt++) {
      float s = 0.0f, s2 = 0.0f;
#pragma unroll
      for (int m = 0; m < 4; m++)
#pragma unroll
        for (int v = 0; v < 4; v++) {
          float x = acc[m][nt][v];
          s += x;
          s2 = fmaf(x, x, s2);
        }
      s += __shfl_xor(s, 16, 64);
      s2 += __shfl_xor(s2, 16, 64);
      s += __shfl_xor(s, 32, 64);
      s2 += __shfl_xor(s2, 32, 64);
      float mu = s * (1.0f / 64.0f);
      float var = s2 * (1.0f / 64.0f) - mu * mu;
      float inv = rsqrtf(var + LN_EPS);
#pragma unroll
      for (int m = 0; m < 4; m++)
#pragma unroll
        for (int v = 0; v < 4; v++) {
          float x = (acc[m][nt][v] - mu) * inv;
          x = g4[m][v] * x + b4[m][v];
          acc[m][nt][v] = x > 0.0f ? x : aslope * x;
        }
    }

    if (li < 3) {
      float h[64];
#pragma unroll
      for (int o = 0; o < 64; o++) {
        int srcl = c + 16 * ((o >> 2) & 3);
#pragma unroll
        for (int ntp = 0; ntp < 4; ntp++) {
          float tv = __shfl(acc[o >> 4][ntp][o & 3], srcl, 64);
          if (g == ntp) h[o] = tv;
        }
      }
      u32 hpk_hi[32], hpk_lo[32];
#pragma unroll
      for (int w = 0; w < 32; w++) {
        float f0 = h[2 * w], f1 = h[2 * w + 1];
        u32 h0 = rn_hi32(f0);
        u32 h1 = rn_hi32(f1);
        float l0 = f0 - __uint_as_float(h0);
        float l1 = f1 - __uint_as_float(h1);
        hpk_hi[w] = (h0 >> 16) | h1;
        hpk_lo[w] = rn_b16(l0) | (rn_b16(l1) << 16);
      }
#pragma unroll
      for (int nt = 0; nt < 4; nt++) {
        int src = c + 16 * nt;
#pragma unroll
        for (int ks = 0; ks < 2; ks++)
#pragma unroll
          for (int gw = 0; gw < 4; gw++)
#pragma unroll
            for (int j2 = 0; j2 < 4; j2++) {
              u32 th = (u32)__shfl((int)hpk_hi[16 * ks + 4 * gw + j2], src, 64);
              u32 tl = (u32)__shfl((int)hpk_lo[16 * ks + 4 * gw + j2], src, 64);
              if (g == gw) {
                bhi[nt][ks][j2] = th;
                blo[nt][ks][j2] = tl;
              }
            }
      }
    } else {
      float n_safe = (cnt == 0.0f) ? 1.0f : cnt;
      float rinv = 1.0f / n_safe;
      float msk = ((float)c < cnt) ? 1.0f : 0.0f;
#pragma unroll
      for (int nt = 0; nt < 4; nt++)
#pragma unroll
        for (int m = 0; m < 4; m++) {
          f32x4 r;
#pragma unroll
          for (int v = 0; v < 4; v++) {
            float x = acc[m][nt][v] * msk;
            x += __shfl_xor(x, 1, 64);
            x += __shfl_xor(x, 2, 64);
            x += __shfl_xor(x, 4, 64);
            x += __shfl_xor(x, 8, 64);
            r[v] = x * rinv;
          }
          if (c == 0)
            *(f32x4*)(out + (size_t)(pbase + nt) * 64 + 16 * m + 4 * g) = r;
        }
    }
  }
}

// ---------------------------------------------------------------------------
extern "C" void kernel_launch(void* const* d_in, const int* in_sizes, int n_in,
                              void* d_out, int out_size, void* d_ws, size_t ws_size,
                              hipStream_t stream) {
  const float* points  = (const float*)d_in[0];
  const float* x       = (const float*)d_in[1];
  const int*   mask    = (const int*)d_in[2];
  const float* W0      = (const float*)d_in[3];
  const float* b0      = (const float*)d_in[4];
  const float* Wh      = (const float*)d_in[5];
  const float* bh      = (const float*)d_in[6];
  const float* ln_g    = (const float*)d_in[7];
  const float* ln_b    = (const float*)d_in[8];
  const float* prelu_a = (const float*)d_in[9];
  float* out = (float*)d_out;

  char* ws = (char*)d_ws;
  int*   knn  = (int*)ws;                                    // 1 MB
  float* p_c  = (float*)(ws + (1 << 20));                    // 4 MB
  float* p_n  = (float*)(ws + (1 << 20) + (4 << 20));        // 4 MB
  u32x4* whi  = (u32x4*)(ws + (9 << 20));                    // 32 KB
  u32x4* wlo  = (u32x4*)(ws + (9 << 20) + (32 << 10));       // 32 KB
  float* ntr  = (float*)(ws + (9 << 20) + (64 << 10));       // 64 B
  u32*   H0   = (u32*)(ws + ((size_t)10 << 20));             // 32 MB
  u32*   H1   = (u32*)(ws + ((size_t)42 << 20));             // 32 MB

  front_kernel<<<24 + 4096 + 256, 256, 0, stream>>>(
      Wh, whi, wlo, mask, ntr, points, knn, x, W0, b0, p_c, p_n);

  if (ws_size >= ((size_t)74 << 20)) {
    // global-transport path: layerA (layer0 + hidden-0 fused) + 3 layers
    layerA_kernel<<<2048, 128, 0, stream>>>(p_c, p_n, knn, whi, wlo, bh,
                                            ln_g, ln_b, prelu_a, H0);
    layer_kernel<<<2048, 128, 0, stream>>>(H0, H1, whi, wlo, bh, ln_g, ln_b,
                                           prelu_a, ntr, out, 1, 0);
    layer_kernel<<<2048, 128, 0, stream>>>(H1, H0, whi, wlo, bh, ln_g, ln_b,
                                           prelu_a, ntr, out, 2, 0);
    layer_kernel<<<2048, 128, 0, stream>>>(H0, H1, whi, wlo, bh, ln_g, ln_b,
                                           prelu_a, ntr, out, 3, 1);
  } else {
    // fallback: byte-exact R13 mlp (passed 3x)
    mlp_mfma3_kernel<<<2048, 128, 0, stream>>>(p_c, p_n, knn, whi, wlo, bh,
                                               ln_g, ln_b, prelu_a, ntr, out);
  }
}

// Round 26
// 187.178 us; speedup vs baseline: 1.0358x; 1.0020x over previous
//
#include <hip/hip_runtime.h>
#include <hip/hip_bf16.h>
#include <math.h>

#define N_ 1024
#define KNN_K 16
#define LN_EPS 1e-5f

typedef unsigned long long u64;
typedef unsigned int u32;
typedef __attribute__((ext_vector_type(4))) float f32x4;
typedef __attribute__((ext_vector_type(8))) short short8;
typedef __attribute__((ext_vector_type(2))) unsigned int u32x2;
typedef __attribute__((ext_vector_type(4))) unsigned int u32x4;

// Round-to-nearest-even bf16 helpers.
__device__ __forceinline__ u32 rn_hi32(float v) {  // bf16 bits in high half
  u32 u = __float_as_uint(v);
  return (u + 0x7FFFu + ((u >> 16) & 1u)) & 0xFFFF0000u;
}
__device__ __forceinline__ u32 rn_b16(float v) {   // bf16 bits as 16-bit value
  u32 u = __float_as_uint(v);
  return (u + 0x7FFFu + ((u >> 16) & 1u)) >> 16;
}
__device__ __forceinline__ u64 umin64(u64 a, u64 b) { return a < b ? a : b; }

// ---------------------------------------------------------------------------
// front: BYTE-IDENTICAL to R24 (passed; decoded-winner consume).
// ---------------------------------------------------------------------------
__global__ __launch_bounds__(256) void front_kernel(
    const float* __restrict__ Wh, u32x4* __restrict__ whi,
    u32x4* __restrict__ wlo, const int* __restrict__ mask,
    float* __restrict__ ntr, const float* __restrict__ points,
    int* __restrict__ knn, const float* __restrict__ x,
    const float* __restrict__ W0, const float* __restrict__ b0,
    float* __restrict__ p_c, float* __restrict__ p_n) {
  __shared__ float SM[4096];              // 16 KiB
  const int blk = blockIdx.x;
  const int t = threadIdx.x;

  if (blk < 8) {
    int idx = blk * 256 + t;
    int lane = idx & 63;
    int ks = (idx >> 6) & 1;
    int m = (idx >> 7) & 3;
    int li = idx >> 9;
    int o = 16 * m + (lane & 15);
    int k0 = 32 * ks + 8 * (lane >> 4);
    const float* w = Wh + li * 4096 + o * 64 + k0;
    u32x4 hi, lo;
#pragma unroll
    for (int j = 0; j < 4; j++) {
      float f0 = w[2 * j], f1 = w[2 * j + 1];
      u32 h0 = rn_hi32(f0);
      u32 h1 = rn_hi32(f1);
      float l0 = f0 - __uint_as_float(h0);
      float l1 = f1 - __uint_as_float(h1);
      hi[j] = (h0 >> 16) | h1;
      lo[j] = rn_b16(l0) | (rn_b16(l1) << 16);
    }
    int fi = ((li * 4 + m) * 2 + ks) * 64 + lane;
    whi[fi] = hi;
    wlo[fi] = lo;
  } else if (blk < 24) {
    int b = blk - 8;
    int s = 0;
    for (int e = t; e < N_; e += 256) s += mask[b * N_ + e];
    for (int off = 32; off; off >>= 1) s += __shfl_xor(s, off, 64);
    int* accI = (int*)SM;
    int wave = t >> 6, lane = t & 63;
    if (lane == 0) accI[wave] = s;
    __syncthreads();
    if (t == 0) ntr[b] = (float)(accI[0] + accI[1] + accI[2] + accI[3]);
  } else if (blk < 24 + 4096) {
#pragma clang fp contract(off)
    float* px = SM;
    float* py = SM + 1024;
    float* pz = SM + 2048;
    float* minf = SM + 3072;
    int kb = blk - 24;
    int b = kb >> 8;
    int qbase = (kb & 255) << 2;
    for (int j = t; j < N_; j += 256) {
      const float* p = points + ((size_t)(b * N_ + j)) * 3;
      px[j] = p[0];
      py[j] = p[1];
      pz[j] = p[2];
      minf[j] = mask[b * N_ + j] ? 0.0f : __builtin_inff();
    }
    __syncthreads();
    int wave = t >> 6, lane = t & 63;
    int n = qbase + wave;
    float qx = px[n], qy = py[n], qz = pz[n];
    u64 key[16];
#pragma unroll
    for (int c = 0; c < 16; c++) {
      int j = lane + (c << 6);
      float dx = qx - px[j];
      float dy = qy - py[j];
      float dz = qz - pz[j];
      float d2 = dx * dx + dy * dy + dz * dz;
      d2 = d2 + minf[j];
      key[c] = ((u64)__float_as_uint(d2) << 32) | (u32)j;
    }
    int* dst = knn + ((size_t)(b * N_ + n)) * KNN_K;
    for (int s = 0; s < 16; s++) {
      // depth-4 tree min over the 16 local keys (exact; min associative)
      u64 a0 = umin64(key[0], key[1]);
      u64 a1 = umin64(key[2], key[3]);
      u64 a2 = umin64(key[4], key[5]);
      u64 a3 = umin64(key[6], key[7]);
      u64 a4 = umin64(key[8], key[9]);
      u64 a5 = umin64(key[10], key[11]);
      u64 a6 = umin64(key[12], key[13]);
      u64 a7 = umin64(key[14], key[15]);
      u64 b0_ = umin64(a0, a1);
      u64 b1_ = umin64(a2, a3);
      u64 b2_ = umin64(a4, a5);
      u64 b3_ = umin64(a6, a7);
      u64 m = umin64(umin64(b0_, b1_), umin64(b2_, b3_));
#pragma unroll
      for (int off = 32; off; off >>= 1) {
        u64 o = __shfl_xor(m, off, 64);
        if (o < m) m = o;
      }
      if (lane == 0) dst[s] = (int)(m & 0xFFFFFFFFu);
      // consume via decoded winner (R22/R24-proven): j=lane+64c -> wl, wc
      int wl = (int)(m & 63u), wc = (int)((m >> 6) & 15u);
#pragma unroll
      for (int c = 0; c < 16; c++)
        if (lane == wl && c == wc) key[c] = ~0ULL;
    }
  } else {
    float* W = SM;                        // one 64x64 matrix at a time
    int pb = blk - (24 + 4096);
    int wave = t >> 6, lane = t & 63;
    int pbase = pb * 64 + wave * 16;
    // ---- pass A: Wc = W0a + W0b -> p_c ----
    for (int e = t; e < 4096; e += 256) {
      int o = e & 63, i = e >> 6;         // stride-1 LDS writes
      W[i * 64 + o] = W0[o * 128 + i] + W0[o * 128 + 64 + i];
    }
    __syncthreads();
    for (int it = 0; it < 16; it++) {
      int p = pbase + it;
      const float* xr = x + (size_t)__builtin_amdgcn_readfirstlane(p) * 64;
      float pc = b0[lane];
#pragma unroll
      for (int i = 0; i < 64; i++) pc = fmaf(xr[i], W[i * 64 + lane], pc);
      p_c[(size_t)p * 64 + lane] = pc;
    }
    __syncthreads();                      // WAR: reads done before reload
    // ---- pass B: Wn = W0b -> p_n ----
    for (int e = t; e < 4096; e += 256) {
      int o = e & 63, i = e >> 6;
      W[i * 64 + o] = W0[o * 128 + 64 + i];
    }
    __syncthreads();
    for (int it = 0; it < 16; it++) {
      int p = pbase + it;
      const float* xr = x + (size_t)__builtin_amdgcn_readfirstlane(p) * 64;
      float pn = 0.0f;
#pragma unroll
      for (int i = 0; i < 64; i++) pn = fmaf(xr[i], W[i * 64 + lane], pn);
      p_n[(size_t)p * 64 + lane] = pn;
    }
  }
}

// ---------------------------------------------------------------------------
// layerA — BYTE-IDENTICAL to R20/R21/R23/R24 (passed): layer0 + hidden-0.
// ---------------------------------------------------------------------------
__global__ __launch_bounds__(128) void layerA_kernel(
    const float* __restrict__ p_c, const float* __restrict__ p_n,
    const int* __restrict__ knn_, const u32x4* __restrict__ whi,
    const u32x4* __restrict__ wlo, const float* __restrict__ bh,
    const float* __restrict__ ln_g, const float* __restrict__ ln_b,
    const float* __restrict__ prelu_a, u32* __restrict__ Hout) {
  const int t = threadIdx.x;
  const int wv = t >> 6, l = t & 63;
  const int c = l & 15;
  const int g = l >> 4;
  const int pbase = blockIdx.x * 8 + wv * 4;
  const int b = pbase >> 10;

  u32x4 bhi[4][2], blo[4][2];

  {
    float h[64];
    int p0 = pbase + g;
    int j = knn_[(size_t)p0 * 16 + c];
    const float4* pc4 = reinterpret_cast<const float4*>(p_c + (size_t)p0 * 64);
    const float4* pn4 = reinterpret_cast<const float4*>(p_n + (size_t)((b << 10) + j) * 64);
#pragma unroll
    for (int q = 0; q < 16; q++) {
      float4 a = pc4[q], v = pn4[q];
      h[q * 4 + 0] = a.x - v.x;
      h[q * 4 + 1] = a.y - v.y;
      h[q * 4 + 2] = a.z - v.z;
      h[q * 4 + 3] = a.w - v.w;
    }
    float s = 0.0f, s2 = 0.0f;
#pragma unroll
    for (int o = 0; o < 64; o++) { s += h[o]; s2 += h[o] * h[o]; }
    float mu = s * (1.0f / 64.0f);
    float var = s2 * (1.0f / 64.0f) - mu * mu;
    float inv = rsqrtf(var + LN_EPS);
    float aslope = prelu_a[0];
#pragma unroll
    for (int o = 0; o < 64; o++) {
      float v = ln_g[o] * ((h[o] - mu) * inv) + ln_b[o];
      h[o] = v > 0.0f ? v : aslope * v;
    }
    u32 hpk_hi[32], hpk_lo[32];
#pragma unroll
    for (int w = 0; w < 32; w++) {
      float f0 = h[2 * w], f1 = h[2 * w + 1];
      u32 h0 = rn_hi32(f0);
      u32 h1 = rn_hi32(f1);
      float l0 = f0 - __uint_as_float(h0);
      float l1 = f1 - __uint_as_float(h1);
      hpk_hi[w] = (h0 >> 16) | h1;
      hpk_lo[w] = rn_b16(l0) | (rn_b16(l1) << 16);
    }
#pragma unroll
    for (int nt = 0; nt < 4; nt++) {
      int src = c + 16 * nt;
#pragma unroll
      for (int ks = 0; ks < 2; ks++)
#pragma unroll
        for (int gw = 0; gw < 4; gw++)
#pragma unroll
          for (int j2 = 0; j2 < 4; j2++) {
            u32 th = (u32)__shfl((int)hpk_hi[16 * ks + 4 * gw + j2], src, 64);
            u32 tl = (u32)__shfl((int)hpk_lo[16 * ks + 4 * gw + j2], src, 64);
            if (g == gw) {
              bhi[nt][ks][j2] = th;
              blo[nt][ks][j2] = tl;
            }
          }
    }
  }

  const int li = 0;
  f32x4 bias4[4];
#pragma unroll
  for (int m = 0; m < 4; m++)
    bias4[m] = *(const f32x4*)(bh + li * 64 + 16 * m + 4 * g);

  f32x4 acc[4][4];
#pragma unroll
  for (int m = 0; m < 4; m++)
#pragma unroll
    for (int nt = 0; nt < 4; nt++) acc[m][nt] = bias4[m];

#pragma unroll
  for (int ks = 0; ks < 2; ks++)
#pragma unroll
    for (int m = 0; m < 4; m++) {
      int fi = ((li * 4 + m) * 2 + ks) * 64 + l;
      short8 ah = __builtin_bit_cast(short8, whi[fi]);
      short8 al = __builtin_bit_cast(short8, wlo[fi]);
#pragma unroll
      for (int nt = 0; nt < 4; nt++) {
        short8 bh_ = __builtin_bit_cast(short8, bhi[nt][ks]);
        short8 bl_ = __builtin_bit_cast(short8, blo[nt][ks]);
        acc[m][nt] = __builtin_amdgcn_mfma_f32_16x16x32_bf16(ah, bh_, acc[m][nt], 0, 0, 0);
        acc[m][nt] = __builtin_amdgcn_mfma_f32_16x16x32_bf16(ah, bl_, acc[m][nt], 0, 0, 0);
        acc[m][nt] = __builtin_amdgcn_mfma_f32_16x16x32_bf16(al, bh_, acc[m][nt], 0, 0, 0);
      }
    }

  f32x4 g4[4], b4[4];
#pragma unroll
  for (int m = 0; m < 4; m++) {
    g4[m] = *(const f32x4*)(ln_g + (li + 1) * 64 + 16 * m + 4 * g);
    b4[m] = *(const f32x4*)(ln_b + (li + 1) * 64 + 16 * m + 4 * g);
  }
  float aslope = prelu_a[li + 1];
#pragma unroll
  for (int nt = 0; nt < 4; nt++) {
    float s = 0.0f, s2 = 0.0f;
#pragma unroll
    for (int m = 0; m < 4; m++)
#pragma unroll
      for (int v = 0; v < 4; v++) {
        float x = acc[m][nt][v];
        s += x;
        s2 = fmaf(x, x, s2);
      }
    s += __shfl_xor(s, 16, 64);
    s2 += __shfl_xor(s2, 16, 64);
    s += __shfl_xor(s, 32, 64);
    s2 += __shfl_xor(s2, 32, 64);
    float mu = s * (1.0f / 64.0f);
    float var = s2 * (1.0f / 64.0f) - mu * mu;
    float inv = rsqrtf(var + LN_EPS);
#pragma unroll
    for (int m = 0; m < 4; m++)
#pragma unroll
      for (int v = 0; v < 4; v++) {
        float x = (acc[m][nt][v] - mu) * inv;
        x = g4[m][v] * x + b4[m][v];
        acc[m][nt][v] = x > 0.0f ? x : aslope * x;
      }
  }

#pragma unroll
  for (int nt = 0; nt < 4; nt++) {
    size_t eb = ((size_t)(pbase + nt) * 16 + c) * 32;
#pragma unroll
    for (int m = 0; m < 4; m++) {
      u32x2 v;
      v[0] = rn_b16(acc[m][nt][0]) | (rn_b16(acc[m][nt][1]) << 16);
      v[1] = rn_b16(acc[m][nt][2]) | (rn_b16(acc[m][nt][3]) << 16);
      *(u32x2*)(Hout + eb + 8 * m + 2 * g) = v;
    }
  }
}

// ---------------------------------------------------------------------------
// layer (global path): BYTE-IDENTICAL to R17 (passed). Double-buffered H.
// ---------------------------------------------------------------------------
__global__ __launch_bounds__(128) void layer_kernel(
    const u32* __restrict__ Hin, u32* __restrict__ Hout,
    const u32x4* __restrict__ whi, const u32x4* __restrict__ wlo,
    const float* __restrict__ bh, const float* __restrict__ ln_g,
    const float* __restrict__ ln_b, const float* __restrict__ prelu_a,
    const float* __restrict__ ntr, float* __restrict__ out, int li, int last) {
  const int t = threadIdx.x;
  const int wv = t >> 6, l = t & 63;
  const int c = l & 15;
  const int g = l >> 4;
  const int pbase = blockIdx.x * 8 + wv * 4;
  const int b = pbase >> 10;

  u32x4 bw[4][2];
#pragma unroll
  for (int nt = 0; nt < 4; nt++) {
    size_t eb = ((size_t)(pbase + nt) * 16 + c) * 32;
#pragma unroll
    for (int ks = 0; ks < 2; ks++)
      bw[nt][ks] = *(const u32x4*)(Hin + eb + 16 * ks + 4 * g);
  }

  f32x4 bias4[4];
#pragma unroll
  for (int m = 0; m < 4; m++)
    bias4[m] = *(const f32x4*)(bh + li * 64 + 16 * m + 4 * g);

  f32x4 acc[4][4];  // [m][nt]
#pragma unroll
  for (int m = 0; m < 4; m++)
#pragma unroll
    for (int nt = 0; nt < 4; nt++) acc[m][nt] = bias4[m];

#pragma unroll
  for (int ks = 0; ks < 2; ks++)
#pragma unroll
    for (int m = 0; m < 4; m++) {
      int fi = ((li * 4 + m) * 2 + ks) * 64 + l;
      short8 ah = __builtin_bit_cast(short8, whi[fi]);
      short8 al = __builtin_bit_cast(short8, wlo[fi]);
#pragma unroll
      for (int nt = 0; nt < 4; nt++) {
        short8 bb = __builtin_bit_cast(short8, bw[nt][ks]);
        acc[m][nt] = __builtin_amdgcn_mfma_f32_16x16x32_bf16(ah, bb, acc[m][nt], 0, 0, 0);
        acc[m][nt] = __builtin_amdgcn_mfma_f32_16x16x32_bf16(al, bb, acc[m][nt], 0, 0, 0);
      }
    }

  f32x4 g4[4], b4[4];
#pragma unroll
  for (int m = 0; m < 4; m++) {
    g4[m] = *(const f32x4*)(ln_g + (li + 1) * 64 + 16 * m + 4 * g);
    b4[m] = *(const f32x4*)(ln_b + (li + 1) * 64 + 16 * m + 4 * g);
  }
  float aslope = prelu_a[li + 1];
#pragma unroll
  for (int nt = 0; nt < 4; nt++) {
    float s = 0.0f, s2 = 0.0f;
#pragma unroll
    for (int m = 0; m < 4; m++)
#pragma unroll
      for (int v = 0; v < 4; v++) {
        float x = acc[m][nt][v];
        s += x;
        s2 = fmaf(x, x, s2);
      }
    s += __shfl_xor(s, 16, 64);
    s2 += __shfl_xor(s2, 16, 64);
    s += __shfl_xor(s, 32, 64);
    s2 += __shfl_xor(s2, 32, 64);
    float mu = s * (1.0f / 64.0f);
    float var = s2 * (1.0f / 64.0f) - mu * mu;
    float inv = rsqrtf(var + LN_EPS);
#pragma unroll
    for (int m = 0; m < 4; m++)
#pragma unroll
      for (int v = 0; v < 4; v++) {
        float x = (acc[m][nt][v] - mu) * inv;
        x = g4[m][v] * x + b4[m][v];
        acc[m][nt][v] = x > 0.0f ? x : aslope * x;
      }
  }

  if (!last) {
#pragma unroll
    for (int nt = 0; nt < 4; nt++) {
      size_t eb = ((size_t)(pbase + nt) * 16 + c) * 32;
#pragma unroll
      for (int m = 0; m < 4; m++) {
        u32x2 v;
        v[0] = rn_b16(acc[m][nt][0]) | (rn_b16(acc[m][nt][1]) << 16);
        v[1] = rn_b16(acc[m][nt][2]) | (rn_b16(acc[m][nt][3]) << 16);
        *(u32x2*)(Hout + eb + 8 * m + 2 * g) = v;
      }
    }
  } else {
    float cnt = ntr[b];
    float n_safe = (cnt == 0.0f) ? 1.0f : cnt;
    float rinv = 1.0f / n_safe;
    float msk = ((float)c < cnt) ? 1.0f : 0.0f;
#pragma unroll
    for (int nt = 0; nt < 4; nt++)
#pragma unroll
      for (int m = 0; m < 4; m++) {
        f32x4 r;
#pragma unroll
        for (int v = 0; v < 4; v++) {
          float x = acc[m][nt][v] * msk;
          x += __shfl_xor(x, 1, 64);
          x += __shfl_xor(x, 2, 64);
          x += __shfl_xor(x, 4, 64);
          x += __shfl_xor(x, 8, 64);
          r[v] = x * rinv;
        }
        if (c == 0)
          *(f32x4*)(out + (size_t)(pbase + nt) * 64 + 16 * m + 4 * g) = r;
      }
  }
}

// ---------------------------------------------------------------------------
// mlp_mfma3 — BYTE-EXACT R11/R13 kernel (passed 3x). FALLBACK path.
// ---------------------------------------------------------------------------
__global__ __launch_bounds__(128) void mlp_mfma3_kernel(
    const float* __restrict__ p_c, const float* __restrict__ p_n,
    const int* __restrict__ knn_, const u32x4* __restrict__ whi,
    const u32x4* __restrict__ wlo, const float* __restrict__ bh,
    const float* __restrict__ ln_g, const float* __restrict__ ln_b,
    const float* __restrict__ prelu_a, const float* __restrict__ ntr,
    float* __restrict__ out) {
  const int t = threadIdx.x;
  const int wv = t >> 6, l = t & 63;
  const int c = l & 15;
  const int g = l >> 4;
  const int pbase = blockIdx.x * 8 + wv * 4;
  const int b = pbase >> 10;

  u32x4 bhi[4][2], blo[4][2];

  {
    float h[64];
    int p0 = pbase + g;
    int j = knn_[(size_t)p0 * 16 + c];
    const float4* pc4 = reinterpret_cast<const float4*>(p_c + (size_t)p0 * 64);
    const float4* pn4 = reinterpret_cast<const float4*>(p_n + (size_t)((b << 10) + j) * 64);
#pragma unroll
    for (int q = 0; q < 16; q++) {
      float4 a = pc4[q], v = pn4[q];
      h[q * 4 + 0] = a.x - v.x;
      h[q * 4 + 1] = a.y - v.y;
      h[q * 4 + 2] = a.z - v.z;
      h[q * 4 + 3] = a.w - v.w;
    }
    float s = 0.0f, s2 = 0.0f;
#pragma unroll
    for (int o = 0; o < 64; o++) { s += h[o]; s2 += h[o] * h[o]; }
    float mu = s * (1.0f / 64.0f);
    float var = s2 * (1.0f / 64.0f) - mu * mu;
    float inv = rsqrtf(var + LN_EPS);
    float aslope = prelu_a[0];
#pragma unroll
    for (int o = 0; o < 64; o++) {
      float v = ln_g[o] * ((h[o] - mu) * inv) + ln_b[o];
      h[o] = v > 0.0f ? v : aslope * v;
    }
    u32 hpk_hi[32], hpk_lo[32];
#pragma unroll
    for (int w = 0; w < 32; w++) {
      float f0 = h[2 * w], f1 = h[2 * w + 1];
      u32 h0 = rn_hi32(f0);
      u32 h1 = rn_hi32(f1);
      float l0 = f0 - __uint_as_float(h0);
      float l1 = f1 - __uint_as_float(h1);
      hpk_hi[w] = (h0 >> 16) | h1;
      hpk_lo[w] = rn_b16(l0) | (rn_b16(l1) << 16);
    }
#pragma unroll
    for (int nt = 0; nt < 4; nt++) {
      int src = c + 16 * nt;
#pragma unroll
      for (int ks = 0; ks < 2; ks++)
#pragma unroll
        for (int gw = 0; gw < 4; gw++)
#pragma unroll
          for (int j2 = 0; j2 < 4; j2++) {
            u32 th = (u32)__shfl((int)hpk_hi[16 * ks + 4 * gw + j2], src, 64);
            u32 tl = (u32)__shfl((int)hpk_lo[16 * ks + 4 * gw + j2], src, 64);
            if (g == gw) {
              bhi[nt][ks][j2] = th;
              blo[nt][ks][j2] = tl;
            }
          }
    }
  }

  float cnt = ntr[b];

#pragma unroll 1
  for (int li = 0; li < 4; li++) {
    f32x4 bias4[4];
#pragma unroll
    for (int m = 0; m < 4; m++)
      bias4[m] = *(const f32x4*)(bh + li * 64 + 16 * m + 4 * g);

    f32x4 acc[4][4];
#pragma unroll
    for (int m = 0; m < 4; m++)
#pragma unroll
      for (int nt = 0; nt < 4; nt++) acc[m][nt] = bias4[m];

#pragma unroll
    for (int ks = 0; ks < 2; ks++)
#pragma unroll
      for (int m = 0; m < 4; m++) {
        int fi = ((li * 4 + m) * 2 + ks) * 64 + l;
        short8 ah = __builtin_bit_cast(short8, whi[fi]);
        short8 al = __builtin_bit_cast(short8, wlo[fi]);
#pragma unroll
        for (int nt = 0; nt < 4; nt++) {
          short8 bh_ = __builtin_bit_cast(short8, bhi[nt][ks]);
          short8 bl_ = __builtin_bit_cast(short8, blo[nt][ks]);
          acc[m][nt] = __builtin_amdgcn_mfma_f32_16x16x32_bf16(ah, bh_, acc[m][nt], 0, 0, 0);
          acc[m][nt] = __builtin_amdgcn_mfma_f32_16x16x32_bf16(ah, bl_, acc[m][nt], 0, 0, 0);
          acc[m][nt] = __builtin_amdgcn_mfma_f32_16x16x32_bf16(al, bh_, acc[m][nt], 0, 0, 0);
        }
      }

    f32x4 g4[4], b4[4];
#pragma unroll
    for (int m = 0; m < 4; m++) {
      g4[m] = *(const f32x4*)(ln_g + (li + 1) * 64 + 16 * m + 4 * g);
      b4[m] = *(const f32x4*)(ln_b + (li + 1) * 64 + 16 * m + 4 * g);
    }
    float aslope = prelu_a[li + 1];
#pragma unroll
    for (int nt = 0; nt < 4; nt++) {
      float s = 0.0f, s2 = 0.0f;
#pragma unroll
      for (int m = 0; m < 4; m++)
#pragma unroll
        for (int v = 0; v < 4; v++) {
          float x = acc[m][nt][v];
          s += x;
          s2 = fmaf(x, x, s2);
        }
      s += __shfl_xor(s, 16, 64);
      s2 += __shfl_xor(s2, 16, 64);
      s += __shfl_xor(s, 32, 64);
      s2 += __shfl_xor(s2, 32, 64);
      float mu = s * (1.0f / 64.0f);
      float var = s2 * (1.0f / 64.0f) - mu * mu;
      float inv = rsqrtf(var + LN_EPS);
#pragma unroll
      for (int m = 0; m < 4; m++)
#pragma unroll
        for (int v = 0; v < 4; v++) {
          float x = (acc[m][nt][v] - mu) * inv;
          x = g4[m][v] * x + b4[m][v];
          acc[m][nt][v] = x > 0.0f ? x : aslope * x;
        }
    }

    if (li < 3) {
      float h[64];
#pragma unroll
      for (int o = 0; o < 64; o++) {
        int srcl = c + 16 * ((o >> 2) & 3);
#pragma unroll
        for (int ntp = 0; ntp < 4; ntp++) {
          float tv = __shfl(acc[o >> 4][ntp][o & 3], srcl, 64);
          if (g == ntp) h[o] = tv;
        }
      }
      u32 hpk_hi[32], hpk_lo[32];
#pragma unroll
      for (int w = 0; w < 32; w++) {
        float f0 = h[2 * w], f1 = h[2 * w + 1];
        u32 h0 = rn_hi32(f0);
        u32 h1 = rn_hi32(f1);
        float l0 = f0 - __uint_as_float(h0);
        float l1 = f1 - __uint_as_float(h1);
        hpk_hi[w] = (h0 >> 16) | h1;
        hpk_lo[w] = rn_b16(l0) | (rn_b16(l1) << 16);
      }
#pragma unroll
      for (int nt = 0; nt < 4; nt++) {
        int src = c + 16 * nt;
#pragma unroll
        for (int ks = 0; ks < 2; ks++)
#pragma unroll
          for (int gw = 0; gw < 4; gw++)
#pragma unroll
            for (int j2 = 0; j2 < 4; j2++) {
              u32 th = (u32)__shfl((int)hpk_hi[16 * ks + 4 * gw + j2], src, 64);
              u32 tl = (u32)__shfl((int)hpk_lo[16 * ks + 4 * gw + j2], src, 64);
              if (g == gw) {
                bhi[nt][ks][j2] = th;
                blo[nt][ks][j2] = tl;
              }
            }
      }
    } else {
      float n_safe = (cnt == 0.0f) ? 1.0f : cnt;
      float rinv = 1.0f / n_safe;
      float msk = ((float)c < cnt) ? 1.0f : 0.0f;
#pragma unroll
      for (int nt = 0; nt < 4; nt++)
#pragma unroll
        for (int m = 0; m < 4; m++) {
          f32x4 r;
#pragma unroll
          for (int v = 0; v < 4; v++) {
            float x = acc[m][nt][v] * msk;
            x += __shfl_xor(x, 1, 64);
            x += __shfl_xor(x, 2, 64);
            x += __shfl_xor(x, 4, 64);
            x += __shfl_xor(x, 8, 64);
            r[v] = x * rinv;
          }
          if (c == 0)
            *(f32x4*)(out + (size_t)(pbase + nt) * 64 + 16 * m + 4 * g) = r;
        }
    }
  }
}

// ---------------------------------------------------------------------------
extern "C" void kernel_launch(void* const* d_in, const int* in_sizes, int n_in,
                              void* d_out, int out_size, void* d_ws, size_t ws_size,
                              hipStream_t stream) {
  const float* points  = (const float*)d_in[0];
  const float* x       = (const float*)d_in[1];
  const int*   mask    = (const int*)d_in[2];
  const float* W0      = (const float*)d_in[3];
  const float* b0      = (const float*)d_in[4];
  const float* Wh      = (const float*)d_in[5];
  const float* bh      = (const float*)d_in[6];
  const float* ln_g    = (const float*)d_in[7];
  const float* ln_b    = (const float*)d_in[8];
  const float* prelu_a = (const float*)d_in[9];
  float* out = (float*)d_out;

  char* ws = (char*)d_ws;
  int*   knn  = (int*)ws;                                    // 1 MB
  float* p_c  = (float*)(ws + (1 << 20));                    // 4 MB
  float* p_n  = (float*)(ws + (1 << 20) + (4 << 20));        // 4 MB
  u32x4* whi  = (u32x4*)(ws + (9 << 20));                    // 32 KB
  u32x4* wlo  = (u32x4*)(ws + (9 << 20) + (32 << 10));       // 32 KB
  float* ntr  = (float*)(ws + (9 << 20) + (64 << 10));       // 64 B
  u32*   H0   = (u32*)(ws + ((size_t)10 << 20));             // 32 MB
  u32*   H1   = (u32*)(ws + ((size_t)42 << 20));             // 32 MB

  front_kernel<<<24 + 4096 + 256, 256, 0, stream>>>(
      Wh, whi, wlo, mask, ntr, points, knn, x, W0, b0, p_c, p_n);

  if (ws_size >= ((size_t)74 << 20)) {
    // global-transport path: layerA (layer0 + hidden-0 fused) + 3 layers
    layerA_kernel<<<2048, 128, 0, stream>>>(p_c, p_n, knn, whi, wlo, bh,
                                            ln_g, ln_b, prelu_a, H0);
    layer_kernel<<<2048, 128, 0, stream>>>(H0, H1, whi, wlo, bh, ln_g, ln_b,
                                           prelu_a, ntr, out, 1, 0);
    layer_kernel<<<2048, 128, 0, stream>>>(H1, H0, whi, wlo, bh, ln_g, ln_b,
                                           prelu_a, ntr, out, 2, 0);
    layer_kernel<<<2048, 128, 0, stream>>>(H0, H1, whi, wlo, bh, ln_g, ln_b,
                                           prelu_a, ntr, out, 3, 1);
  } else {
    // fallback: byte-exact R13 mlp (passed 3x)
    mlp_mfma3_kernel<<<2048, 128, 0, stream>>>(p_c, p_n, knn, whi, wlo, bh,
                                               ln_g, ln_b, prelu_a, ntr, out);
  }
}